// Round 8
// baseline (974.843 us; speedup 1.0000x reference)
//
#include <hip/hip_runtime.h>
#include <math.h>

#define NBATCH 8
#define NPTS   2048
#define NPOINT 512
#define KNB    16
#define NROWS  (NBATCH*NPOINT*KNB)   // 65536

// mega-kernel block roles
#define TRANS_BASE  NBATCH          // 8..263   transpose (256)
#define ZERO_BID    (NBATCH + 256)  // 264      zero L1-stat region
#define CONV_BASE   (NBATCH + 257)  // 265..968 bank conv (704 blocks, pair-wise)
#define KNN_BASE    (NBATCH + 257 + 704)    // 969..1992 knn+score+L0 (1024 blocks)
#define MEGA_GRID   (KNN_BASE + 1024)       // 1993
#define RCTR_TARGET 960             // 256 transpose + 704 conv

typedef unsigned short ushort_t;
typedef unsigned int   uint_t;
typedef unsigned long long ull_t;
typedef __attribute__((ext_vector_type(8))) short  short8;   // 8 bf16 (4 VGPRs)
typedef __attribute__((ext_vector_type(4))) float  f32x4;    // MFMA C/D
typedef __attribute__((ext_vector_type(2))) float  f32x2;    // packed-FP32 pair

// g_bankF element offsets (bf16, MFMA-fragment-major: [kc][nt][lane][8])
#define B0_OFF 0        // COUT=64,  K=512  -> 32768 elems
#define B1_OFF 32768    // COUT=128, K=512  -> 65536
#define B2_OFF 98304    // COUT=256, K=1024 -> 262144
#define BT_TOT 360448

// LDS-only workgroup barrier: orders LDS ops across waves WITHOUT draining
// vmcnt, so global loads stay in flight.
#define LDS_BARRIER() asm volatile("s_waitcnt lgkmcnt(0)\n\ts_barrier" ::: "memory")

// ---------------------------------------------------------------------------
// Scratch in static __device__ globals. Referenced ONLY in device code.
// g_S layout (R8): [l][m][row]  (was [l][row][m]) -> GEMM combine reads a
// clean float4 of 4 consecutive rows' scores for fixed (l,m).
// ---------------------------------------------------------------------------
__device__ __align__(16) int      g_fidx [NBATCH * NPOINT];       //  16 KB
__device__ __align__(16) int      g_fready[NBATCH * NPOINT];      //  16 KB flags (0 = not ready, else far+1)
__device__            int      g_rctr = 0;                        // transpose+conv arrival counter (monotonic across reps)
__device__ __align__(16) int      g_knn [NROWS];                  // 256 KB
__device__ __align__(16) float    g_sums[1024];                   //   4 KB  [0,128)=L0 stats, [256,512)=L1 stats
__device__ __align__(16) float    g_pT  [NBATCH * NPTS * 64];     //   4 MB
__device__ __align__(16) float    g_S   [(size_t)3 * 8 * NROWS];  //   6 MB  [l][m][row]
__device__ __align__(16) float    g_act1[(size_t)NROWS * 64];     //  16 MB
__device__ __align__(16) float    g_act2[(size_t)NROWS * 128];    //  32 MB
__device__ __align__(16) ushort_t g_bankF[BT_TOT];                // 704 KB bf16 fragments

// f32 -> bf16 round-to-nearest-even (finite inputs).
__device__ __forceinline__ ushort_t f2bf(float f) {
    uint_t u = __float_as_uint(f);
    return (ushort_t)((u + 0x7FFFu + ((u >> 16) & 1u)) >> 16);
}

// DPP-shifted copy of a u64 key (bound_ctrl=1: invalid lanes read 0, the
// identity for unsigned max of our keys).
template<int CTRL>
__device__ __forceinline__ ull_t dpp_u64(ull_t k) {
    int lo = (int)(uint_t)k;
    int hi = (int)(uint_t)(k >> 32);
    int slo = __builtin_amdgcn_update_dpp(0, lo, CTRL, 0xF, 0xF, true);
    int shi = __builtin_amdgcn_update_dpp(0, hi, CTRL, 0xF, 0xF, true);
    return ((ull_t)(uint_t)shi << 32) | (uint_t)slo;
}

__device__ __forceinline__ ull_t dpp_max_u64(ull_t key) {
    { ull_t s = dpp_u64<0x111>(key); if (s > key) key = s; }  // row_shr:1
    { ull_t s = dpp_u64<0x112>(key); if (s > key) key = s; }  // row_shr:2
    { ull_t s = dpp_u64<0x114>(key); if (s > key) key = s; }  // row_shr:4
    { ull_t s = dpp_u64<0x118>(key); if (s > key) key = s; }  // row_shr:8
    { ull_t s = dpp_u64<0x142>(key); if (s > key) key = s; }  // row_bcast:15
    { ull_t s = dpp_u64<0x143>(key); if (s > key) key = s; }  // row_bcast:31
    return key;   // wave max in lane 63
}

// u32 variant (values are non-negative f32 bit patterns -> unsigned max
// == float max; bound_ctrl=1 zero-fill is the identity).
template<int CTRL>
__device__ __forceinline__ uint_t dpp_u32(uint_t v) {
    return (uint_t)__builtin_amdgcn_update_dpp(0, (int)v, CTRL, 0xF, 0xF, true);
}

__device__ __forceinline__ uint_t dpp_max_u32(uint_t v) {
    { uint_t s = dpp_u32<0x111>(v); if (s > v) v = s; }
    { uint_t s = dpp_u32<0x112>(v); if (s > v) v = s; }
    { uint_t s = dpp_u32<0x114>(v); if (s > v) v = s; }
    { uint_t s = dpp_u32<0x118>(v); if (s > v) v = s; }
    { uint_t s = dpp_u32<0x142>(v); if (s > v) v = s; }
    { uint_t s = dpp_u32<0x143>(v); if (s > v) v = s; }
    return v;   // wave max in lane 63
}

// Convert one bank element PAIR into fragment-major bf16 layout.
template<int COUT>
__device__ __forceinline__ void bank_frag2(const float* __restrict__ bank,
                                           uint_t* __restrict__ dst, int le) {
    const int j = le & 7;
    const int lane = (le >> 3) & 63;
    const int rem = le >> 9;
    constexpr int NTL = COUT / 16;
    const int nt = rem % NTL;
    const int kc = rem / NTL;
    const int q = lane >> 4, nlo = lane & 15;
    const int k = kc * 32 + q * 8 + j;
    const int n = nt * 16 + nlo;
    const float f0 = bank[(size_t)k * COUT + n];
    const float f1 = bank[(size_t)(k + 1) * COUT + n];
    dst[le >> 1] = (uint_t)f2bf(f0) | ((uint_t)f2bf(f1) << 16);
}

// ---------------------------------------------------------------------------
// mega_kernel: identical to R7 except g_S indexing ([l][m][row]).
// ---------------------------------------------------------------------------
__global__ __launch_bounds__(256, 5) void mega_kernel(
    const float* __restrict__ xyz, const float* __restrict__ points,
    const float* __restrict__ bank0, const float* __restrict__ bank1,
    const float* __restrict__ bank2, float* __restrict__ dout,
    const float* __restrict__ nrm, const float* __restrict__ Xa,
    const float* __restrict__ Ya,
    const float* __restrict__ w1_0, const float* __restrict__ b1_0,
    const float* __restrict__ w2_0, const float* __restrict__ b2_0,
    const float* __restrict__ w1_1, const float* __restrict__ b1_1,
    const float* __restrict__ w2_1, const float* __restrict__ b2_1,
    const float* __restrict__ w1_2, const float* __restrict__ b1_2,
    const float* __restrict__ w2_2, const float* __restrict__ b2_2) {
    __shared__ float smem[3 * NPTS];     // 24 KB, multi-role
    __shared__ ull_t s_key[2][4];
    const int bid = blockIdx.x;
    const int t = threadIdx.x;

    if (bid >= NBATCH) {
        if (bid < ZERO_BID) {
            // ---- transpose points (one 64x64 tile, 16 elems/thread) ----
            float (*tile)[65] = reinterpret_cast<float(*)[65]>(smem);
            const int blk = bid - TRANS_BASE;
            const int b = blk >> 5;
            const int n0 = (blk & 31) * 64;
            const int lane = t & 63, q = t >> 6;   // q in [0,4)
            #pragma unroll
            for (int i = 0; i < 16; ++i) {
                int c = q * 16 + i;
                tile[c][lane] = points[(b * 64 + c) * NPTS + n0 + lane];
            }
            __syncthreads();
            #pragma unroll
            for (int i = 0; i < 16; ++i) {
                int n = q * 16 + i;
                g_pT[(size_t)(b * NPTS + n0 + n) * 64 + lane] = tile[lane][n];
            }
            __syncthreads();
            if (t == 0)
                __hip_atomic_fetch_add(&g_rctr, 1, __ATOMIC_RELEASE,
                                       __HIP_MEMORY_SCOPE_AGENT);
            return;
        } else if (bid == ZERO_BID) {
            g_sums[256 + t] = 0.0f;
            return;
        } else if (bid < KNN_BASE) {
            // ---- bank -> fragment-major bf16, element PAIRS (704 blocks) ----
            const int le = ((bid - CONV_BASE) * 256 + t) << 1;   // even elem idx
            if (le < 32768) {
                bank_frag2<64>(bank0, reinterpret_cast<uint_t*>(g_bankF + B0_OFF), le);
            } else if (le < 98304) {
                bank_frag2<128>(bank1, reinterpret_cast<uint_t*>(g_bankF + B1_OFF), le - 32768);
            } else {
                bank_frag2<256>(bank2, reinterpret_cast<uint_t*>(g_bankF + B2_OFF), le - 98304);
            }
            __syncthreads();
            if (t == 0)
                __hip_atomic_fetch_add(&g_rctr, 1, __ATOMIC_RELEASE,
                                       __HIP_MEMORY_SCOPE_AGENT);
            return;
        }

        // ============ knn + score + small_out + fused L0 GEMM ============
        {
            const float* w1p[3] = {w1_0, w1_1, w1_2};
            const float* b1p[3] = {b1_0, b1_1, b1_2};
            const float* w2p[3] = {w2_0, w2_1, w2_2};
            const float* b2p[3] = {b2_0, b2_1, b2_2};
            #pragma unroll
            for (int l = 0; l < 3; ++l) {
                if (t < 160) smem[l * 160 + t] = w1p[l][t];
                if (t < 16)  smem[480 + l * 16 + t] = b1p[l][t];
                if (t < 128) smem[528 + l * 128 + t] = w2p[l][t];
                if (t < 8)   smem[912 + l * 8 + t] = b2p[l][t];
            }
        }
        __syncthreads();

        const int wave = (bid - KNN_BASE) * 4 + (t >> 6);   // = b*512 + p
        const int lane = t & 63;
        const int b = wave >> 9;
        const int p = wave & 511;
        const float* xb = xyz + b * 3 * NPTS;

        // ---- spin until FPS publishes this query ----
        int fv = __hip_atomic_load(&g_fready[wave], __ATOMIC_RELAXED,
                                   __HIP_MEMORY_SCOPE_AGENT);
        while (fv == 0) {
            __builtin_amdgcn_s_sleep(15);
            fv = __hip_atomic_load(&g_fready[wave], __ATOMIC_RELAXED,
                                   __HIP_MEMORY_SCOPE_AGENT);
        }
        if (lane == 0)
            __hip_atomic_store(&g_fready[wave], 0, __ATOMIC_RELAXED,
                               __HIP_MEMORY_SCOPE_AGENT);
        const int fi = (fv - 1) & (NPTS - 1);
        int nmine = 0;

        {
            #pragma clang fp contract(off)
            float ax = xb[fi];
            float ay = xb[NPTS + fi];
            float az = xb[2*NPTS + fi];
            float sa = ax*ax + ay*ay; sa = sa + az*az;
            float d[32];
            #pragma unroll
            for (int j = 0; j < 32; ++j) {
                int pp = j * 64 + lane;
                float bx = xb[pp];
                float by = xb[NPTS + pp];
                float bz = xb[2*NPTS + pp];
                float sb = bx*bx + by*by; sb = sb + bz*bz;
                float dot = ax*bx + ay*by; dot = dot + az*bz;
                float t1 = sa + sb;
                float t2 = 2.0f * dot;
                d[j] = t1 - t2;
            }
            for (int r = 0; r < KNB; ++r) {
                float best = 1e30f; int bi = 0x7fffffff;
                #pragma unroll
                for (int j = 0; j < 32; ++j) {
                    if (d[j] < best) { best = d[j]; bi = j * 64 + lane; }
                }
                uint_t ub = __float_as_uint(best);
                ub = (ub & 0x80000000u) ? ~ub : (ub | 0x80000000u);
                ull_t key = ((ull_t)(~ub) << 32) | (uint_t)(~bi);
                key = dpp_max_u64(key);
                uint_t wlo = (uint_t)__builtin_amdgcn_readlane((int)(uint_t)key, 63);
                bi = (int)(~wlo) & (NPTS - 1);
                if (lane == 0) g_knn[wave * KNB + r] = bi;
                if (lane == r) nmine = bi;
                int rl = bi & 63, rs = bi >> 6;
                if (lane == rl) {
                    #pragma unroll
                    for (int j = 0; j < 32; ++j) if (j == rs) d[j] = 1e30f;
                }
            }
        }

        // ---- small outputs for this query ----
        {
            const int n0 = __builtin_amdgcn_readlane(nmine, 0) & (NPTS - 1);
            if (lane < 12) {
                const int arr = lane / 3, a = lane % 3;
                const float* src = (arr == 0) ? xyz : (arr == 1) ? nrm
                                 : (arr == 2) ? Xa : Ya;
                const int idx = (arr == 0) ? fi : n0;
                dout[arr * 12288 + (b*3 + a) * NPOINT + p] =
                    src[(b*3 + a) * NPTS + idx];
            }
        }

        // ---- score phase: lanes 0-15 each handle row (b,p,k=lane) ----
        if (lane < 16) {
            const int row = wave * KNB + lane;
            const int n = nmine & (NPTS - 1);
            const float* nb = nrm + b * 3 * NPTS;
            const float* Xb = Xa  + b * 3 * NPTS;
            const float* Yb = Ya  + b * 3 * NPTS;
            float gx, gy, gz, sq, draw, nnv;
            {
                #pragma clang fp contract(off)
                gx = xb[n]        - xb[fi];
                gy = xb[NPTS + n] - xb[NPTS + fi];
                gz = xb[2*NPTS+n] - xb[2*NPTS+fi];
                sq = gx*gx + gy*gy;
                sq = sq + gz*gz;
                draw = sqrtf(sq + 1e-10f);
                nnv = sqrtf(sq);
            }
            float dmin = draw, dmax = draw;
            #pragma unroll
            for (int m = 1; m < 16; m <<= 1) {
                dmin = fminf(dmin, __shfl_xor(dmin, m, 16));
                dmax = fmaxf(dmax, __shfl_xor(dmax, m, 16));
            }
            float dist;
            {
                #pragma clang fp contract(off)
                dist = (draw - dmin) / ((dmax - dmin) + 1e-10f);
            }
            float nx = nb[n], ny = nb[NPTS+n], nz = nb[2*NPTS+n];
            float Xx = Xb[n], Xy = Xb[NPTS+n], Xz = Xb[2*NPTS+n];
            float Yx = Yb[n], Yy = Yb[NPTS+n], Yz = Yb[2*NPTS+n];
            float g[10];
            g[0]=gx; g[1]=gy; g[2]=gz; g[3]=dist; g[4]=nx; g[5]=ny; g[6]=nz;
            {
                float vs[3][3] = {{nx,ny,nz},{Xx,Xy,Xz},{Yx,Yy,Yz}};
                #pragma unroll
                for (int a = 0; a < 3; ++a) {
                    float vx=vs[a][0], vy=vs[a][1], vz=vs[a][2];
                    float dot, nv;
                    {
                        #pragma clang fp contract(off)
                        dot = gx*vx + gy*vy; dot = dot + gz*vz;
                        float s2 = vx*vx + vy*vy; s2 = s2 + vz*vz;
                        nv = sqrtf(s2);
                    }
                    float cc = dot / (nnv * nv + 1e-8f);
                    cc = fminf(1.0f, fmaxf(-1.0f, cc));
                    g[7+a] = acosf(cc) / 3.14159274101257324f;
                }
            }
            #pragma unroll
            for (int l = 0; l < 3; ++l) {
                float h[16];
                #pragma unroll
                for (int i = 0; i < 16; ++i) {
                    float a = smem[480 + l * 16 + i];
                    #pragma unroll
                    for (int j = 0; j < 10; ++j) a += smem[l * 160 + i * 10 + j] * g[j];
                    h[i] = fmaxf(a, 0.0f);
                }
                float e[8]; float mx = -1e30f;
                #pragma unroll
                for (int m = 0; m < 8; ++m) {
                    float a = smem[912 + l * 8 + m];
                    #pragma unroll
                    for (int j = 0; j < 16; ++j) a += smem[528 + l * 128 + m * 16 + j] * h[j];
                    e[m] = a; mx = fmaxf(mx, a);
                }
                float sum = 0.0f;
                #pragma unroll
                for (int m = 0; m < 8; ++m) { e[m] = expf(e[m] - mx); sum += e[m]; }
                // g_S layout [l][m][row]
                #pragma unroll
                for (int m = 0; m < 8; ++m)
                    g_S[((size_t)l * 8 + m) * NROWS + row] = e[m] / sum;
            }
        }

        // ---- all 4 waves rejoin; g_knn/g_S visible (same CU) ----
        __syncthreads();
        if (t == 0) {
            while (__hip_atomic_load(&g_rctr, __ATOMIC_ACQUIRE,
                                     __HIP_MEMORY_SCOPE_AGENT) < RCTR_TARGET)
                __builtin_amdgcn_s_sleep(8);
        }
        __syncthreads();

        // =================== fused L0 GEMM (CIN=64, COUT=64) ===================
        {
            constexpr int NTT0 = 4;   // COUT/16
            constexpr int CCM0 = 2;   // CIN/32
            ushort_t (*AsP)[64][36] = reinterpret_cast<ushort_t(*)[64][36]>(smem + 1024);
            float* s_rs  = smem + 3328;
            float* s_rss = smem + 3392;
            const int w = t >> 6;
            const int q = lane >> 4, nlo = lane & 15;
            const int row0 = (bid - KNN_BASE) * 64;
            const int arow_i = t >> 2, acg = t & 3;
            const int rr = row0 + arow_i;
            const int rb = rr >> 13;
            const int rn = g_knn[rr] & (NPTS - 1);
            const size_t arow = (size_t)(rb * NPTS + rn) * 64;
            float svv[8];
            #pragma unroll
            for (int m = 0; m < 8; ++m) svv[m] = g_S[(size_t)m * NROWS + rr];
            f32x4 acc[4];
            #pragma unroll
            for (int mi = 0; mi < 4; ++mi) acc[mi] = (f32x4){0.f, 0.f, 0.f, 0.f};
            const ushort_t* fbase = g_bankF + B0_OFF + lane * 8;
            union FragU { uint4 u4; uint2 u2[2]; short8 s; };
            FragU B[2];
            B[0].u4 = *reinterpret_cast<const uint4*>(fbase + (size_t)w * 512);
            float vraw[8], vnext[8];
            {
                const float* ap = g_pT + arow + acg * 8;
                float4 fa = *reinterpret_cast<const float4*>(ap);
                float4 fb = *reinterpret_cast<const float4*>(ap + 4);
                vraw[0]=fa.x; vraw[1]=fa.y; vraw[2]=fa.z; vraw[3]=fa.w;
                vraw[4]=fb.x; vraw[5]=fb.y; vraw[6]=fb.z; vraw[7]=fb.w;
            }
            int par = 0;
            for (int cc = 0; cc < CCM0; ++cc) {
                #pragma unroll
                for (int m = 0; m < 8; ++m) {
                    {
                        const float sv = svv[m];
                        uint_t* dst = reinterpret_cast<uint_t*>(&AsP[par][arow_i][acg * 8]);
                        #pragma unroll
                        for (int j = 0; j < 8; j += 2)
                            dst[j >> 1] = (uint_t)f2bf(sv * vraw[j]) |
                                          ((uint_t)f2bf(sv * vraw[j + 1]) << 16);
                    }
                    if (m == 0) {
                        const int ccn = (cc + 1 < CCM0) ? cc + 1 : cc;
                        const float* ap = g_pT + arow + ccn * 32 + acg * 8;
                        float4 fa = *reinterpret_cast<const float4*>(ap);
                        float4 fb = *reinterpret_cast<const float4*>(ap + 4);
                        vnext[0]=fa.x; vnext[1]=fa.y; vnext[2]=fa.z; vnext[3]=fa.w;
                        vnext[4]=fb.x; vnext[5]=fb.y; vnext[6]=fb.z; vnext[7]=fb.w;
                    }
                    {
                        const int kcn = (m < 7) ? ((m + 1) * CCM0 + cc)
                                                : ((cc + 1 < CCM0) ? (cc + 1) : 0);
                        B[(m + 1) & 1].u4 = *reinterpret_cast<const uint4*>(
                            fbase + (size_t)(kcn * NTT0 + w) * 512);
                    }
                    LDS_BARRIER();
                    FragU af[4];
                    #pragma unroll
                    for (int mi = 0; mi < 4; ++mi) {
                        af[mi].u2[0] = *reinterpret_cast<const uint2*>(&AsP[par][mi*16 + nlo][q*8]);
                        af[mi].u2[1] = *reinterpret_cast<const uint2*>(&AsP[par][mi*16 + nlo][q*8 + 4]);
                    }
                    #pragma unroll
                    for (int mi = 0; mi < 4; ++mi)
                        acc[mi] = __builtin_amdgcn_mfma_f32_16x16x32_bf16(
                            af[mi].s, B[m & 1].s, acc[mi], 0, 0, 0);
                    par ^= 1;
                }
                #pragma unroll
                for (int j = 0; j < 8; ++j) vraw[j] = vnext[j];
            }
            #pragma unroll
            for (int mi = 0; mi < 4; ++mi)
                #pragma unroll
                for (int r2 = 0; r2 < 4; ++r2)
                    g_act1[(size_t)(row0 + mi*16 + q*4 + r2) * 64 + w*16 + nlo] = acc[mi][r2];
            float s = 0.f, ss = 0.f;
            #pragma unroll
            for (int mi = 0; mi < 4; ++mi) {
                #pragma unroll
                for (int r2 = 0; r2 < 4; ++r2) {
                    float x = acc[mi][r2];
                    s += x; ss += x * x;
                }
            }
            s  += __shfl_xor(s, 16);  s  += __shfl_xor(s, 32);
            ss += __shfl_xor(ss, 16); ss += __shfl_xor(ss, 32);
            if (q == 0) {
                const int c = w * 16 + nlo;
                s_rs[c] = s;
                s_rss[c] = ss;
            }
            __syncthreads();
            if (t < 64) {
                atomicAdd(&g_sums[t], s_rs[t]);
                atomicAdd(&g_sums[64 + t], s_rss[t]);
            }
        }
        return;
    }

    // ==================== FPS: 4 waves, 8 pts/lane (p = t*8+j) ====================
    {
        #pragma clang fp contract(off)
        const int b = bid;
        const int lane = t & 63, w = t >> 6;   // 4 waves
        const float* xb = xyz + b * 3 * NPTS;
        float* s_x = smem;
        float* s_y = smem + NPTS;
        float* s_z = smem + 2 * NPTS;
        f32x2 xp[4], yp[4], zp[4];
        float d[8];
        {
            const float4* xq = reinterpret_cast<const float4*>(xb + t * 8);
            const float4* yq = reinterpret_cast<const float4*>(xb + NPTS + t * 8);
            const float4* zq = reinterpret_cast<const float4*>(xb + 2 * NPTS + t * 8);
            float4 a0 = xq[0], a1 = xq[1];
            float4 b0 = yq[0], b1 = yq[1];
            float4 c0 = zq[0], c1 = zq[1];
            xp[0] = (f32x2){a0.x, a0.y}; xp[1] = (f32x2){a0.z, a0.w};
            xp[2] = (f32x2){a1.x, a1.y}; xp[3] = (f32x2){a1.z, a1.w};
            yp[0] = (f32x2){b0.x, b0.y}; yp[1] = (f32x2){b0.z, b0.w};
            yp[2] = (f32x2){b1.x, b1.y}; yp[3] = (f32x2){b1.z, b1.w};
            zp[0] = (f32x2){c0.x, c0.y}; zp[1] = (f32x2){c0.z, c0.w};
            zp[2] = (f32x2){c1.x, c1.y}; zp[3] = (f32x2){c1.z, c1.w};
            *reinterpret_cast<float4*>(s_x + t * 8)     = a0;
            *reinterpret_cast<float4*>(s_x + t * 8 + 4) = a1;
            *reinterpret_cast<float4*>(s_y + t * 8)     = b0;
            *reinterpret_cast<float4*>(s_y + t * 8 + 4) = b1;
            *reinterpret_cast<float4*>(s_z + t * 8)     = c0;
            *reinterpret_cast<float4*>(s_z + t * 8 + 4) = c1;
            #pragma unroll
            for (int j = 0; j < 8; ++j) d[j] = 1e10f;
        }
        __syncthreads();
        __builtin_amdgcn_s_setprio(2);   // shield the serial chain
        int far = 0;
        for (int i = 0; i < NPOINT; ++i) {
            if (t == 0) {
                g_fidx[b * NPOINT + i] = far;
                __hip_atomic_store(&g_fready[b * NPOINT + i], far + 1,
                                   __ATOMIC_RELAXED, __HIP_MEMORY_SCOPE_AGENT);
            }
            const float cx = s_x[far], cy = s_y[far], cz = s_z[far];
            const f32x2 cxp = (f32x2){cx, cx};
            const f32x2 cyp = (f32x2){cy, cy};
            const f32x2 czp = (f32x2){cz, cz};
            uint_t bb = 0u;
            #pragma unroll
            for (int a = 0; a < 4; ++a) {
                f32x2 dx = xp[a] - cxp;           // v_pk ops, exact IEEE
                f32x2 dy = yp[a] - cyp;
                f32x2 dz = zp[a] - czp;
                f32x2 s2 = dx*dx + dy*dy;         // contract(off): no fma
                s2 = s2 + dz*dz;
                float dn0 = fminf(d[2*a],   s2[0]);
                float dn1 = fminf(d[2*a+1], s2[1]);
                d[2*a] = dn0; d[2*a+1] = dn1;
                uint_t u0 = __float_as_uint(dn0);  // d >= 0: bits monotone
                uint_t u1 = __float_as_uint(dn1);
                bb = (u0 > bb) ? u0 : bb;
                bb = (u1 > bb) ? u1 : bb;
            }
            uint_t wm = dpp_max_u32(bb);
            const uint_t wbits = (uint_t)__builtin_amdgcn_readlane((int)wm, 63);
            int li = 8;
            #pragma unroll
            for (int j = 7; j >= 0; --j)
                li = (__float_as_uint(d[j]) == wbits) ? j : li;
            ull_t mk = __ballot(li < 8);              // nonempty by construction
            const int fl = __ffsll((unsigned long long)mk) - 1;   // lowest lane
            const int wj = __builtin_amdgcn_readlane(li, fl);
            const int wp = (((w << 6) + fl) << 3) + wj;   // this wave's winner p
            if (lane == 0) s_key[i & 1][w] = ((ull_t)wbits << 32) | (uint_t)(~wp);
            LDS_BARRIER();
            const ull_t* kb = s_key[i & 1];
            ull_t k0 = kb[0], k1 = kb[1], k2 = kb[2], k3 = kb[3];
            if (k1 > k0) k0 = k1;
            if (k3 > k2) k2 = k3;
            if (k2 > k0) k0 = k2;
            far = (int)(~(uint_t)k0) & (NPTS - 1);
        }
    }
}

// ---------------------------------------------------------------------------
// MFMA PAConv GEMM v10 (layers 1 and 2): algebraic restructure.
//   out[row,o] = sum_m S[row,m] * (sum_c F[row,c] * bank[m,c,o])
// Stage relu(BN(F)) to bf16 ONCE (8x less staging VALU than staging S_m*F per
// (cc,m); one fewer rounding -> slightly MORE accurate). A-fragments fully
// register-resident (af[CCM][4]); ZERO barriers in the MFMA loop (As is
// read-only after one LDS_BARRIER). B fragments (same g_bankF, kc=m*CCM+cc)
// streamed double-buffered; S applied as f32 combine on the accumulator.
// ---------------------------------------------------------------------------
template<int LAYER, int CIN, int COUT>
__global__ __launch_bounds__(256, 2) void gemm_kernel(const float* __restrict__ gamma,
                                                      const float* __restrict__ beta,
                                                      float* __restrict__ dout) {
    const float* __restrict__ A = (LAYER == 1) ? g_act1 : g_act2;
    float* __restrict__ O = (LAYER == 1) ? g_act2 : dout;
    constexpr int NTT = COUT / 16;    // total col tiles
    constexpr int NTW = NTT / 4;      // col tiles per wave
    constexpr int CCM = CIN / 32;     // K-chunks per m
    constexpr int PADC = CIN + 4;     // pad -> 2-way (free) LDS conflicts on frag reads
    constexpr int CPT = CIN / 4;      // staged elems per thread
    constexpr int BOFF = (LAYER == 1) ? B1_OFF : B2_OFF;
    __shared__ ushort_t As[64][PADC];
    __shared__ float s_scale[CIN];
    __shared__ float s_shift[CIN];
    __shared__ float s_rs[(LAYER < 2) ? COUT : 1];
    __shared__ float s_rss[(LAYER < 2) ? COUT : 1];

    const int t = threadIdx.x;
    const int lane = t & 63, w = t >> 6;
    const int q = lane >> 4, nlo = lane & 15;
    const int row0 = blockIdx.x * 64;
    const int arow_i = t >> 2, acg = t & 3;

    if constexpr (LAYER == 2) {
        // zero L0-stat region for the next rep (no reader in this rep's
        // remaining launches; next adders are next rep's mega knn blocks).
        if (blockIdx.x == 0 && t < 128) g_sums[t] = 0.0f;
    }

    {
        const float* sb = (LAYER == 1) ? g_sums : (g_sums + 256);
        if (t < CIN) {
            float mu  = sb[t] * (1.0f / 65536.0f);
            float var = sb[CIN + t] * (1.0f / 65536.0f) - mu * mu;
            var = fmaxf(var, 0.0f);
            float sc = gamma[t] / sqrtf(var + 1e-5f);
            s_scale[t] = sc;
            s_shift[t] = beta[t] - mu * sc;
        }
        __syncthreads();
    }

    // ---- stage relu(BN(F)) -> bf16, ONCE ----
    {
        const size_t arow = (size_t)(row0 + arow_i) * CIN;
        const float* ap = A + arow + acg * CPT;
        uint_t* dst = reinterpret_cast<uint_t*>(&As[arow_i][acg * CPT]);
        #pragma unroll
        for (int jj = 0; jj < CPT; jj += 8) {
            float4 fa = *reinterpret_cast<const float4*>(ap + jj);
            float4 fb = *reinterpret_cast<const float4*>(ap + jj + 4);
            float v[8] = {fa.x, fa.y, fa.z, fa.w, fb.x, fb.y, fb.z, fb.w};
            #pragma unroll
            for (int k2 = 0; k2 < 8; ++k2) {
                const int c = acg * CPT + jj + k2;
                v[k2] = fmaxf(v[k2] * s_scale[c] + s_shift[c], 0.f);
            }
            #pragma unroll
            for (int k2 = 0; k2 < 8; k2 += 2)
                dst[(jj + k2) >> 1] = (uint_t)f2bf(v[k2]) | ((uint_t)f2bf(v[k2+1]) << 16);
        }
    }
    LDS_BARRIER();

    // ---- A fragments fully register-resident ----
    union FragU { uint4 u4; uint2 u2[2]; short8 s; };
    FragU af[CCM][4];
    #pragma unroll
    for (int kc = 0; kc < CCM; ++kc)
        #pragma unroll
        for (int mi = 0; mi < 4; ++mi) {
            af[kc][mi].u2[0] = *reinterpret_cast<const uint2*>(&As[mi*16 + nlo][kc*32 + q*8]);
            af[kc][mi].u2[1] = *reinterpret_cast<const uint2*>(&As[mi*16 + nlo][kc*32 + q*8 + 4]);
        }

    f32x4 acc[4][NTW];
    #pragma unroll
    for (int mi = 0; mi < 4; ++mi)
        #pragma unroll
        for (int ni = 0; ni < NTW; ++ni) acc[mi][ni] = (f32x4){0.f, 0.f, 0.f, 0.f};

    const ushort_t* fbase = g_bankF + BOFF + lane * 8;
    const float* Sbase = g_S + (size_t)LAYER * 8 * NROWS;

    // B stream: step s = m*NTW + ni; double-buffered by parity
    FragU Bf[2][CCM];
    #pragma unroll
    for (int cc = 0; cc < CCM; ++cc)
        Bf[0][cc].u4 = *reinterpret_cast<const uint4*>(
            fbase + (size_t)(cc * NTT + w * NTW) * 512);

    #pragma unroll
    for (int m = 0; m < 8; ++m) {
        f32x4 Sv[4];
        #pragma unroll
        for (int mi = 0; mi < 4; ++mi)
            Sv[mi] = *reinterpret_cast<const f32x4*>(
                Sbase + (size_t)m * NROWS + row0 + mi*16 + q*4);
        #pragma unroll
        for (int ni = 0; ni < NTW; ++ni) {
            const int s = m * NTW + ni;
            if (s + 1 < 8 * NTW) {
                const int ns = s + 1, nm = ns / NTW, nni = ns % NTW;
                #pragma unroll
                for (int cc = 0; cc < CCM; ++cc)
                    Bf[(s + 1) & 1][cc].u4 = *reinterpret_cast<const uint4*>(
                        fbase + (size_t)((nm * CCM + cc) * NTT + w * NTW + nni) * 512);
            }
            f32x4 a2[4];
            #pragma unroll
            for (int mi = 0; mi < 4; ++mi) a2[mi] = (f32x4){0.f, 0.f, 0.f, 0.f};
            #pragma unroll
            for (int cc = 0; cc < CCM; ++cc)
                #pragma unroll
                for (int mi = 0; mi < 4; ++mi)
                    a2[mi] = __builtin_amdgcn_mfma_f32_16x16x32_bf16(
                        af[cc][mi].s, Bf[s & 1][cc].s, a2[mi], 0, 0, 0);
            #pragma unroll
            for (int mi = 0; mi < 4; ++mi)
                acc[mi][ni] += Sv[mi] * a2[mi];   // f32 combine (per-row score)
        }
    }

    if constexpr (LAYER == 2) {
        const int bp0 = row0 >> 4;
        #pragma unroll
        for (int mi = 0; mi < 4; ++mi) {
            const int bp = bp0 + mi;
            const int b = bp >> 9, p = bp & 511;
            #pragma unroll
            for (int ni = 0; ni < NTW; ++ni) {
                float mv = fmaxf(fmaxf(acc[mi][ni][0], acc[mi][ni][1]),
                                 fmaxf(acc[mi][ni][2], acc[mi][ni][3]));
                mv = fmaxf(mv, __shfl_xor(mv, 16));
                mv = fmaxf(mv, __shfl_xor(mv, 32));
                if (lane < 16) {
                    const int col = w * 64 + ni * 16 + nlo;
                    O[(size_t)(b * 256 + col) * NPOINT + p] = mv;
                }
            }
        }
    } else {
        #pragma unroll
        for (int mi = 0; mi < 4; ++mi)
            #pragma unroll
            for (int ni = 0; ni < NTW; ++ni)
                #pragma unroll
                for (int r2 = 0; r2 < 4; ++r2)
                    O[(size_t)(row0 + mi*16 + q*4 + r2) * COUT + w*NTW*16 + ni*16 + nlo] = acc[mi][ni][r2];
        #pragma unroll
        for (int ni = 0; ni < NTW; ++ni) {
            float s = 0.f, ss = 0.f;
            #pragma unroll
            for (int mi = 0; mi < 4; ++mi) {
                #pragma unroll
                for (int r2 = 0; r2 < 4; ++r2) {
                    float x = acc[mi][ni][r2];
                    s += x; ss += x * x;
                }
            }
            s  += __shfl_xor(s, 16);  s  += __shfl_xor(s, 32);
            ss += __shfl_xor(ss, 16); ss += __shfl_xor(ss, 32);
            if (q == 0) {
                const int c = w * NTW * 16 + ni * 16 + nlo;   // unique owner
                s_rs[c] = s;
                s_rss[c] = ss;
            }
        }
        __syncthreads();
        if (t < COUT) {
            float* sb = g_sums + 256;
            atomicAdd(&sb[t], s_rs[t]);
            atomicAdd(&sb[COUT + t], s_rss[t]);
        }
    }
}

// ---------------------------------------------------------------------------
extern "C" void kernel_launch(void* const* d_in, const int* in_sizes, int n_in,
                              void* d_out, int out_size, void* d_ws, size_t ws_size,
                              hipStream_t stream) {
    const float* xyz    = (const float*)d_in[0];
    const float* nrm    = (const float*)d_in[1];
    const float* Xa     = (const float*)d_in[2];
    const float* Ya     = (const float*)d_in[3];
    const float* points = (const float*)d_in[4];
    const float* w1_0 = (const float*)d_in[5];  const float* b1_0 = (const float*)d_in[6];
    const float* w2_0 = (const float*)d_in[7];  const float* b2_0 = (const float*)d_in[8];
    const float* bank0 = (const float*)d_in[9];
    const float* g0 = (const float*)d_in[10];   const float* be0 = (const float*)d_in[11];
    const float* w1_1 = (const float*)d_in[12]; const float* b1_1 = (const float*)d_in[13];
    const float* w2_1 = (const float*)d_in[14]; const float* b2_1 = (const float*)d_in[15];
    const float* bank1 = (const float*)d_in[16];
    const float* g1 = (const float*)d_in[17];   const float* be1 = (const float*)d_in[18];
    const float* w1_2 = (const float*)d_in[19]; const float* b1_2 = (const float*)d_in[20];
    const float* w2_2 = (const float*)d_in[21]; const float* b2_2 = (const float*)d_in[22];
    const float* bank2 = (const float*)d_in[23];
    float* out = (float*)d_out;
    (void)d_ws; (void)ws_size; (void)in_sizes; (void)n_in; (void)out_size;

    // mega: fps + transpose + zero(L1 stats) + bank conv + knn/score/small_out/L0-GEMM
    mega_kernel<<<MEGA_GRID, 256, 0, stream>>>(xyz, points, bank0, bank1, bank2, out,
                                               nrm, Xa, Ya,
                                               w1_0, b1_0, w2_0, b2_0,
                                               w1_1, b1_1, w2_1, b2_1,
                                               w1_2, b1_2, w2_2, b2_2);
    // layer 1 (v10): BN0+relu staged once -> raw act2 + BN stats
    gemm_kernel<1, 64, 128><<<1024, 256, 0, stream>>>(g0, be0, nullptr);
    // layer 2 (v10): BN1+relu staged once -> fused max-k + transpose to d_out
    //                (also zeroes L0-stat region for the next rep)
    gemm_kernel<2, 128, 256><<<1024, 256, 0, stream>>>(g1, be1, out + 49152);
}

// Round 9
// 477.634 us; speedup vs baseline: 2.0410x; 2.0410x over previous
//
#include <hip/hip_runtime.h>
#include <math.h>

#define NBATCH 8
#define NPTS   2048
#define NPOINT 512
#define KNB    16
#define NROWS  (NBATCH*NPOINT*KNB)   // 65536

// mega-kernel block roles
#define TRANS_BASE  NBATCH          // 8..263   transpose (256)
#define ZERO_BID    (NBATCH + 256)  // 264      zero L1-stat region
#define CONV_BASE   (NBATCH + 257)  // 265..968 bank conv (704 blocks, pair-wise)
#define KNN_BASE    (NBATCH + 257 + 704)    // 969..1992 knn+score+L0 (1024 blocks)
#define MEGA_GRID   (KNN_BASE + 1024)       // 1993
#define RCTR_TARGET 960             // 256 transpose + 704 conv

typedef unsigned short ushort_t;
typedef unsigned int   uint_t;
typedef unsigned long long ull_t;
typedef __attribute__((ext_vector_type(8))) short  short8;   // 8 bf16 (4 VGPRs)
typedef __attribute__((ext_vector_type(4))) float  f32x4;    // MFMA C/D
typedef __attribute__((ext_vector_type(2))) float  f32x2;    // packed-FP32 pair

// g_bankF element offsets (bf16, MFMA-fragment-major: [kc][nt][lane][8])
#define B0_OFF 0        // COUT=64,  K=512  -> 32768 elems
#define B1_OFF 32768    // COUT=128, K=512  -> 65536
#define B2_OFF 98304    // COUT=256, K=1024 -> 262144
#define BT_TOT 360448

// LDS-only workgroup barrier: orders LDS ops across waves WITHOUT draining
// vmcnt, so global loads stay in flight.
#define LDS_BARRIER() asm volatile("s_waitcnt lgkmcnt(0)\n\ts_barrier" ::: "memory")

// ---------------------------------------------------------------------------
// Scratch in static __device__ globals. g_S layout: [l][m][row].
// ---------------------------------------------------------------------------
__device__ __align__(16) int      g_fidx [NBATCH * NPOINT];       //  16 KB
__device__ __align__(16) int      g_fready[NBATCH * NPOINT];      //  16 KB flags
__device__            int      g_rctr = 0;                        // arrival counter (monotonic across reps)
__device__ __align__(16) int      g_knn [NROWS];                  // 256 KB
__device__ __align__(16) float    g_sums[1024];                   //   4 KB  [0,128)=L0 stats, [256,512)=L1 stats
__device__ __align__(16) float    g_pT  [NBATCH * NPTS * 64];     //   4 MB
__device__ __align__(16) float    g_S   [(size_t)3 * 8 * NROWS];  //   6 MB  [l][m][row]
__device__ __align__(16) float    g_act1[(size_t)NROWS * 64];     //  16 MB
__device__ __align__(16) float    g_act2[(size_t)NROWS * 128];    //  32 MB
__device__ __align__(16) ushort_t g_bankF[BT_TOT];                // 704 KB bf16 fragments

// f32 -> bf16 round-to-nearest-even (finite inputs).
__device__ __forceinline__ ushort_t f2bf(float f) {
    uint_t u = __float_as_uint(f);
    return (ushort_t)((u + 0x7FFFu + ((u >> 16) & 1u)) >> 16);
}

// DPP-shifted copy of a u64 key (bound_ctrl=1: invalid lanes read 0).
template<int CTRL>
__device__ __forceinline__ ull_t dpp_u64(ull_t k) {
    int lo = (int)(uint_t)k;
    int hi = (int)(uint_t)(k >> 32);
    int slo = __builtin_amdgcn_update_dpp(0, lo, CTRL, 0xF, 0xF, true);
    int shi = __builtin_amdgcn_update_dpp(0, hi, CTRL, 0xF, 0xF, true);
    return ((ull_t)(uint_t)shi << 32) | (uint_t)slo;
}

__device__ __forceinline__ ull_t dpp_max_u64(ull_t key) {
    { ull_t s = dpp_u64<0x111>(key); if (s > key) key = s; }  // row_shr:1
    { ull_t s = dpp_u64<0x112>(key); if (s > key) key = s; }  // row_shr:2
    { ull_t s = dpp_u64<0x114>(key); if (s > key) key = s; }  // row_shr:4
    { ull_t s = dpp_u64<0x118>(key); if (s > key) key = s; }  // row_shr:8
    { ull_t s = dpp_u64<0x142>(key); if (s > key) key = s; }  // row_bcast:15
    { ull_t s = dpp_u64<0x143>(key); if (s > key) key = s; }  // row_bcast:31
    return key;   // wave max in lane 63
}

template<int CTRL>
__device__ __forceinline__ uint_t dpp_u32(uint_t v) {
    return (uint_t)__builtin_amdgcn_update_dpp(0, (int)v, CTRL, 0xF, 0xF, true);
}

__device__ __forceinline__ uint_t dpp_max_u32(uint_t v) {
    { uint_t s = dpp_u32<0x111>(v); if (s > v) v = s; }
    { uint_t s = dpp_u32<0x112>(v); if (s > v) v = s; }
    { uint_t s = dpp_u32<0x114>(v); if (s > v) v = s; }
    { uint_t s = dpp_u32<0x118>(v); if (s > v) v = s; }
    { uint_t s = dpp_u32<0x142>(v); if (s > v) v = s; }
    { uint_t s = dpp_u32<0x143>(v); if (s > v) v = s; }
    return v;   // wave max in lane 63
}

// Convert one bank element PAIR into fragment-major bf16 layout.
template<int COUT>
__device__ __forceinline__ void bank_frag2(const float* __restrict__ bank,
                                           uint_t* __restrict__ dst, int le) {
    const int j = le & 7;
    const int lane = (le >> 3) & 63;
    const int rem = le >> 9;
    constexpr int NTL = COUT / 16;
    const int nt = rem % NTL;
    const int kc = rem / NTL;
    const int q = lane >> 4, nlo = lane & 15;
    const int k = kc * 32 + q * 8 + j;
    const int n = nt * 16 + nlo;
    const float f0 = bank[(size_t)k * COUT + n];
    const float f1 = bank[(size_t)(k + 1) * COUT + n];
    dst[le >> 1] = (uint_t)f2bf(f0) | ((uint_t)f2bf(f1) << 16);
}

// ---------------------------------------------------------------------------
// mega_kernel: unchanged from R8 (verified).
// ---------------------------------------------------------------------------
__global__ __launch_bounds__(256, 5) void mega_kernel(
    const float* __restrict__ xyz, const float* __restrict__ points,
    const float* __restrict__ bank0, const float* __restrict__ bank1,
    const float* __restrict__ bank2, float* __restrict__ dout,
    const float* __restrict__ nrm, const float* __restrict__ Xa,
    const float* __restrict__ Ya,
    const float* __restrict__ w1_0, const float* __restrict__ b1_0,
    const float* __restrict__ w2_0, const float* __restrict__ b2_0,
    const float* __restrict__ w1_1, const float* __restrict__ b1_1,
    const float* __restrict__ w2_1, const float* __restrict__ b2_1,
    const float* __restrict__ w1_2, const float* __restrict__ b1_2,
    const float* __restrict__ w2_2, const float* __restrict__ b2_2) {
    __shared__ float smem[3 * NPTS];     // 24 KB, multi-role
    __shared__ ull_t s_key[2][4];
    const int bid = blockIdx.x;
    const int t = threadIdx.x;

    if (bid >= NBATCH) {
        if (bid < ZERO_BID) {
            // ---- transpose points (one 64x64 tile, 16 elems/thread) ----
            float (*tile)[65] = reinterpret_cast<float(*)[65]>(smem);
            const int blk = bid - TRANS_BASE;
            const int b = blk >> 5;
            const int n0 = (blk & 31) * 64;
            const int lane = t & 63, q = t >> 6;   // q in [0,4)
            #pragma unroll
            for (int i = 0; i < 16; ++i) {
                int c = q * 16 + i;
                tile[c][lane] = points[(b * 64 + c) * NPTS + n0 + lane];
            }
            __syncthreads();
            #pragma unroll
            for (int i = 0; i < 16; ++i) {
                int n = q * 16 + i;
                g_pT[(size_t)(b * NPTS + n0 + n) * 64 + lane] = tile[lane][n];
            }
            __syncthreads();
            if (t == 0)
                __hip_atomic_fetch_add(&g_rctr, 1, __ATOMIC_RELEASE,
                                       __HIP_MEMORY_SCOPE_AGENT);
            return;
        } else if (bid == ZERO_BID) {
            g_sums[256 + t] = 0.0f;
            return;
        } else if (bid < KNN_BASE) {
            // ---- bank -> fragment-major bf16, element PAIRS (704 blocks) ----
            const int le = ((bid - CONV_BASE) * 256 + t) << 1;   // even elem idx
            if (le < 32768) {
                bank_frag2<64>(bank0, reinterpret_cast<uint_t*>(g_bankF + B0_OFF), le);
            } else if (le < 98304) {
                bank_frag2<128>(bank1, reinterpret_cast<uint_t*>(g_bankF + B1_OFF), le - 32768);
            } else {
                bank_frag2<256>(bank2, reinterpret_cast<uint_t*>(g_bankF + B2_OFF), le - 98304);
            }
            __syncthreads();
            if (t == 0)
                __hip_atomic_fetch_add(&g_rctr, 1, __ATOMIC_RELEASE,
                                       __HIP_MEMORY_SCOPE_AGENT);
            return;
        }

        // ============ knn + score + small_out + fused L0 GEMM ============
        {
            const float* w1p[3] = {w1_0, w1_1, w1_2};
            const float* b1p[3] = {b1_0, b1_1, b1_2};
            const float* w2p[3] = {w2_0, w2_1, w2_2};
            const float* b2p[3] = {b2_0, b2_1, b2_2};
            #pragma unroll
            for (int l = 0; l < 3; ++l) {
                if (t < 160) smem[l * 160 + t] = w1p[l][t];
                if (t < 16)  smem[480 + l * 16 + t] = b1p[l][t];
                if (t < 128) smem[528 + l * 128 + t] = w2p[l][t];
                if (t < 8)   smem[912 + l * 8 + t] = b2p[l][t];
            }
        }
        __syncthreads();

        const int wave = (bid - KNN_BASE) * 4 + (t >> 6);   // = b*512 + p
        const int lane = t & 63;
        const int b = wave >> 9;
        const int p = wave & 511;
        const float* xb = xyz + b * 3 * NPTS;

        // ---- spin until FPS publishes this query ----
        int fv = __hip_atomic_load(&g_fready[wave], __ATOMIC_RELAXED,
                                   __HIP_MEMORY_SCOPE_AGENT);
        while (fv == 0) {
            __builtin_amdgcn_s_sleep(15);
            fv = __hip_atomic_load(&g_fready[wave], __ATOMIC_RELAXED,
                                   __HIP_MEMORY_SCOPE_AGENT);
        }
        if (lane == 0)
            __hip_atomic_store(&g_fready[wave], 0, __ATOMIC_RELAXED,
                               __HIP_MEMORY_SCOPE_AGENT);
        const int fi = (fv - 1) & (NPTS - 1);
        int nmine = 0;

        {
            #pragma clang fp contract(off)
            float ax = xb[fi];
            float ay = xb[NPTS + fi];
            float az = xb[2*NPTS + fi];
            float sa = ax*ax + ay*ay; sa = sa + az*az;
            float d[32];
            #pragma unroll
            for (int j = 0; j < 32; ++j) {
                int pp = j * 64 + lane;
                float bx = xb[pp];
                float by = xb[NPTS + pp];
                float bz = xb[2*NPTS + pp];
                float sb = bx*bx + by*by; sb = sb + bz*bz;
                float dot = ax*bx + ay*by; dot = dot + az*bz;
                float t1 = sa + sb;
                float t2 = 2.0f * dot;
                d[j] = t1 - t2;
            }
            for (int r = 0; r < KNB; ++r) {
                float best = 1e30f; int bi = 0x7fffffff;
                #pragma unroll
                for (int j = 0; j < 32; ++j) {
                    if (d[j] < best) { best = d[j]; bi = j * 64 + lane; }
                }
                uint_t ub = __float_as_uint(best);
                ub = (ub & 0x80000000u) ? ~ub : (ub | 0x80000000u);
                ull_t key = ((ull_t)(~ub) << 32) | (uint_t)(~bi);
                key = dpp_max_u64(key);
                uint_t wlo = (uint_t)__builtin_amdgcn_readlane((int)(uint_t)key, 63);
                bi = (int)(~wlo) & (NPTS - 1);
                if (lane == 0) g_knn[wave * KNB + r] = bi;
                if (lane == r) nmine = bi;
                int rl = bi & 63, rs = bi >> 6;
                if (lane == rl) {
                    #pragma unroll
                    for (int j = 0; j < 32; ++j) if (j == rs) d[j] = 1e30f;
                }
            }
        }

        // ---- small outputs for this query ----
        {
            const int n0 = __builtin_amdgcn_readlane(nmine, 0) & (NPTS - 1);
            if (lane < 12) {
                const int arr = lane / 3, a = lane % 3;
                const float* src = (arr == 0) ? xyz : (arr == 1) ? nrm
                                 : (arr == 2) ? Xa : Ya;
                const int idx = (arr == 0) ? fi : n0;
                dout[arr * 12288 + (b*3 + a) * NPOINT + p] =
                    src[(b*3 + a) * NPTS + idx];
            }
        }

        // ---- score phase: lanes 0-15 each handle row (b,p,k=lane) ----
        if (lane < 16) {
            const int row = wave * KNB + lane;
            const int n = nmine & (NPTS - 1);
            const float* nb = nrm + b * 3 * NPTS;
            const float* Xb = Xa  + b * 3 * NPTS;
            const float* Yb = Ya  + b * 3 * NPTS;
            float gx, gy, gz, sq, draw, nnv;
            {
                #pragma clang fp contract(off)
                gx = xb[n]        - xb[fi];
                gy = xb[NPTS + n] - xb[NPTS + fi];
                gz = xb[2*NPTS+n] - xb[2*NPTS+fi];
                sq = gx*gx + gy*gy;
                sq = sq + gz*gz;
                draw = sqrtf(sq + 1e-10f);
                nnv = sqrtf(sq);
            }
            float dmin = draw, dmax = draw;
            #pragma unroll
            for (int m = 1; m < 16; m <<= 1) {
                dmin = fminf(dmin, __shfl_xor(dmin, m, 16));
                dmax = fmaxf(dmax, __shfl_xor(dmax, m, 16));
            }
            float dist;
            {
                #pragma clang fp contract(off)
                dist = (draw - dmin) / ((dmax - dmin) + 1e-10f);
            }
            float nx = nb[n], ny = nb[NPTS+n], nz = nb[2*NPTS+n];
            float Xx = Xb[n], Xy = Xb[NPTS+n], Xz = Xb[2*NPTS+n];
            float Yx = Yb[n], Yy = Yb[NPTS+n], Yz = Yb[2*NPTS+n];
            float g[10];
            g[0]=gx; g[1]=gy; g[2]=gz; g[3]=dist; g[4]=nx; g[5]=ny; g[6]=nz;
            {
                float vs[3][3] = {{nx,ny,nz},{Xx,Xy,Xz},{Yx,Yy,Yz}};
                #pragma unroll
                for (int a = 0; a < 3; ++a) {
                    float vx=vs[a][0], vy=vs[a][1], vz=vs[a][2];
                    float dot, nv;
                    {
                        #pragma clang fp contract(off)
                        dot = gx*vx + gy*vy; dot = dot + gz*vz;
                        float s2 = vx*vx + vy*vy; s2 = s2 + vz*vz;
                        nv = sqrtf(s2);
                    }
                    float cc = dot / (nnv * nv + 1e-8f);
                    cc = fminf(1.0f, fmaxf(-1.0f, cc));
                    g[7+a] = acosf(cc) / 3.14159274101257324f;
                }
            }
            #pragma unroll
            for (int l = 0; l < 3; ++l) {
                float h[16];
                #pragma unroll
                for (int i = 0; i < 16; ++i) {
                    float a = smem[480 + l * 16 + i];
                    #pragma unroll
                    for (int j = 0; j < 10; ++j) a += smem[l * 160 + i * 10 + j] * g[j];
                    h[i] = fmaxf(a, 0.0f);
                }
                float e[8]; float mx = -1e30f;
                #pragma unroll
                for (int m = 0; m < 8; ++m) {
                    float a = smem[912 + l * 8 + m];
                    #pragma unroll
                    for (int j = 0; j < 16; ++j) a += smem[528 + l * 128 + m * 16 + j] * h[j];
                    e[m] = a; mx = fmaxf(mx, a);
                }
                float sum = 0.0f;
                #pragma unroll
                for (int m = 0; m < 8; ++m) { e[m] = expf(e[m] - mx); sum += e[m]; }
                // g_S layout [l][m][row]
                #pragma unroll
                for (int m = 0; m < 8; ++m)
                    g_S[((size_t)l * 8 + m) * NROWS + row] = e[m] / sum;
            }
        }

        // ---- all 4 waves rejoin; g_knn/g_S visible (same CU) ----
        __syncthreads();
        if (t == 0) {
            while (__hip_atomic_load(&g_rctr, __ATOMIC_ACQUIRE,
                                     __HIP_MEMORY_SCOPE_AGENT) < RCTR_TARGET)
                __builtin_amdgcn_s_sleep(8);
        }
        __syncthreads();

        // =================== fused L0 GEMM (CIN=64, COUT=64) ===================
        {
            constexpr int NTT0 = 4;   // COUT/16
            constexpr int CCM0 = 2;   // CIN/32
            ushort_t (*AsP)[64][36] = reinterpret_cast<ushort_t(*)[64][36]>(smem + 1024);
            float* s_rs  = smem + 3328;
            float* s_rss = smem + 3392;
            const int w = t >> 6;
            const int q = lane >> 4, nlo = lane & 15;
            const int row0 = (bid - KNN_BASE) * 64;
            const int arow_i = t >> 2, acg = t & 3;
            const int rr = row0 + arow_i;
            const int rb = rr >> 13;
            const int rn = g_knn[rr] & (NPTS - 1);
            const size_t arow = (size_t)(rb * NPTS + rn) * 64;
            float svv[8];
            #pragma unroll
            for (int m = 0; m < 8; ++m) svv[m] = g_S[(size_t)m * NROWS + rr];
            f32x4 acc[4];
            #pragma unroll
            for (int mi = 0; mi < 4; ++mi) acc[mi] = (f32x4){0.f, 0.f, 0.f, 0.f};
            const ushort_t* fbase = g_bankF + B0_OFF + lane * 8;
            union FragU { uint4 u4; uint2 u2[2]; short8 s; };
            FragU B[2];
            B[0].u4 = *reinterpret_cast<const uint4*>(fbase + (size_t)w * 512);
            float vraw[8], vnext[8];
            {
                const float* ap = g_pT + arow + acg * 8;
                float4 fa = *reinterpret_cast<const float4*>(ap);
                float4 fb = *reinterpret_cast<const float4*>(ap + 4);
                vraw[0]=fa.x; vraw[1]=fa.y; vraw[2]=fa.z; vraw[3]=fa.w;
                vraw[4]=fb.x; vraw[5]=fb.y; vraw[6]=fb.z; vraw[7]=fb.w;
            }
            int par = 0;
            for (int cc = 0; cc < CCM0; ++cc) {
                #pragma unroll
                for (int m = 0; m < 8; ++m) {
                    {
                        const float sv = svv[m];
                        uint_t* dst = reinterpret_cast<uint_t*>(&AsP[par][arow_i][acg * 8]);
                        #pragma unroll
                        for (int j = 0; j < 8; j += 2)
                            dst[j >> 1] = (uint_t)f2bf(sv * vraw[j]) |
                                          ((uint_t)f2bf(sv * vraw[j + 1]) << 16);
                    }
                    if (m == 0) {
                        const int ccn = (cc + 1 < CCM0) ? cc + 1 : cc;
                        const float* ap = g_pT + arow + ccn * 32 + acg * 8;
                        float4 fa = *reinterpret_cast<const float4*>(ap);
                        float4 fb = *reinterpret_cast<const float4*>(ap + 4);
                        vnext[0]=fa.x; vnext[1]=fa.y; vnext[2]=fa.z; vnext[3]=fa.w;
                        vnext[4]=fb.x; vnext[5]=fb.y; vnext[6]=fb.z; vnext[7]=fb.w;
                    }
                    {
                        const int kcn = (m < 7) ? ((m + 1) * CCM0 + cc)
                                                : ((cc + 1 < CCM0) ? (cc + 1) : 0);
                        B[(m + 1) & 1].u4 = *reinterpret_cast<const uint4*>(
                            fbase + (size_t)(kcn * NTT0 + w) * 512);
                    }
                    LDS_BARRIER();
                    FragU af[4];
                    #pragma unroll
                    for (int mi = 0; mi < 4; ++mi) {
                        af[mi].u2[0] = *reinterpret_cast<const uint2*>(&AsP[par][mi*16 + nlo][q*8]);
                        af[mi].u2[1] = *reinterpret_cast<const uint2*>(&AsP[par][mi*16 + nlo][q*8 + 4]);
                    }
                    #pragma unroll
                    for (int mi = 0; mi < 4; ++mi)
                        acc[mi] = __builtin_amdgcn_mfma_f32_16x16x32_bf16(
                            af[mi].s, B[m & 1].s, acc[mi], 0, 0, 0);
                    par ^= 1;
                }
                #pragma unroll
                for (int j = 0; j < 8; ++j) vraw[j] = vnext[j];
            }
            #pragma unroll
            for (int mi = 0; mi < 4; ++mi)
                #pragma unroll
                for (int r2 = 0; r2 < 4; ++r2)
                    g_act1[(size_t)(row0 + mi*16 + q*4 + r2) * 64 + w*16 + nlo] = acc[mi][r2];
            float s = 0.f, ss = 0.f;
            #pragma unroll
            for (int mi = 0; mi < 4; ++mi) {
                #pragma unroll
                for (int r2 = 0; r2 < 4; ++r2) {
                    float x = acc[mi][r2];
                    s += x; ss += x * x;
                }
            }
            s  += __shfl_xor(s, 16);  s  += __shfl_xor(s, 32);
            ss += __shfl_xor(ss, 16); ss += __shfl_xor(ss, 32);
            if (q == 0) {
                const int c = w * 16 + nlo;
                s_rs[c] = s;
                s_rss[c] = ss;
            }
            __syncthreads();
            if (t < 64) {
                atomicAdd(&g_sums[t], s_rs[t]);
                atomicAdd(&g_sums[64 + t], s_rss[t]);
            }
        }
        return;
    }

    // ==================== FPS: 4 waves, 8 pts/lane (p = t*8+j) ====================
    {
        #pragma clang fp contract(off)
        const int b = bid;
        const int lane = t & 63, w = t >> 6;   // 4 waves
        const float* xb = xyz + b * 3 * NPTS;
        float* s_x = smem;
        float* s_y = smem + NPTS;
        float* s_z = smem + 2 * NPTS;
        f32x2 xp[4], yp[4], zp[4];
        float d[8];
        {
            const float4* xq = reinterpret_cast<const float4*>(xb + t * 8);
            const float4* yq = reinterpret_cast<const float4*>(xb + NPTS + t * 8);
            const float4* zq = reinterpret_cast<const float4*>(xb + 2 * NPTS + t * 8);
            float4 a0 = xq[0], a1 = xq[1];
            float4 b0 = yq[0], b1 = yq[1];
            float4 c0 = zq[0], c1 = zq[1];
            xp[0] = (f32x2){a0.x, a0.y}; xp[1] = (f32x2){a0.z, a0.w};
            xp[2] = (f32x2){a1.x, a1.y}; xp[3] = (f32x2){a1.z, a1.w};
            yp[0] = (f32x2){b0.x, b0.y}; yp[1] = (f32x2){b0.z, b0.w};
            yp[2] = (f32x2){b1.x, b1.y}; yp[3] = (f32x2){b1.z, b1.w};
            zp[0] = (f32x2){c0.x, c0.y}; zp[1] = (f32x2){c0.z, c0.w};
            zp[2] = (f32x2){c1.x, c1.y}; zp[3] = (f32x2){c1.z, c1.w};
            *reinterpret_cast<float4*>(s_x + t * 8)     = a0;
            *reinterpret_cast<float4*>(s_x + t * 8 + 4) = a1;
            *reinterpret_cast<float4*>(s_y + t * 8)     = b0;
            *reinterpret_cast<float4*>(s_y + t * 8 + 4) = b1;
            *reinterpret_cast<float4*>(s_z + t * 8)     = c0;
            *reinterpret_cast<float4*>(s_z + t * 8 + 4) = c1;
            #pragma unroll
            for (int j = 0; j < 8; ++j) d[j] = 1e10f;
        }
        __syncthreads();
        __builtin_amdgcn_s_setprio(2);   // shield the serial chain
        int far = 0;
        for (int i = 0; i < NPOINT; ++i) {
            if (t == 0) {
                g_fidx[b * NPOINT + i] = far;
                __hip_atomic_store(&g_fready[b * NPOINT + i], far + 1,
                                   __ATOMIC_RELAXED, __HIP_MEMORY_SCOPE_AGENT);
            }
            const float cx = s_x[far], cy = s_y[far], cz = s_z[far];
            const f32x2 cxp = (f32x2){cx, cx};
            const f32x2 cyp = (f32x2){cy, cy};
            const f32x2 czp = (f32x2){cz, cz};
            uint_t bb = 0u;
            #pragma unroll
            for (int a = 0; a < 4; ++a) {
                f32x2 dx = xp[a] - cxp;           // v_pk ops, exact IEEE
                f32x2 dy = yp[a] - cyp;
                f32x2 dz = zp[a] - czp;
                f32x2 s2 = dx*dx + dy*dy;         // contract(off): no fma
                s2 = s2 + dz*dz;
                float dn0 = fminf(d[2*a],   s2[0]);
                float dn1 = fminf(d[2*a+1], s2[1]);
                d[2*a] = dn0; d[2*a+1] = dn1;
                uint_t u0 = __float_as_uint(dn0);  // d >= 0: bits monotone
                uint_t u1 = __float_as_uint(dn1);
                bb = (u0 > bb) ? u0 : bb;
                bb = (u1 > bb) ? u1 : bb;
            }
            uint_t wm = dpp_max_u32(bb);
            const uint_t wbits = (uint_t)__builtin_amdgcn_readlane((int)wm, 63);
            int li = 8;
            #pragma unroll
            for (int j = 7; j >= 0; --j)
                li = (__float_as_uint(d[j]) == wbits) ? j : li;
            ull_t mk = __ballot(li < 8);              // nonempty by construction
            const int fl = __ffsll((unsigned long long)mk) - 1;   // lowest lane
            const int wj = __builtin_amdgcn_readlane(li, fl);
            const int wp = (((w << 6) + fl) << 3) + wj;   // this wave's winner p
            if (lane == 0) s_key[i & 1][w] = ((ull_t)wbits << 32) | (uint_t)(~wp);
            LDS_BARRIER();
            const ull_t* kb = s_key[i & 1];
            ull_t k0 = kb[0], k1 = kb[1], k2 = kb[2], k3 = kb[3];
            if (k1 > k0) k0 = k1;
            if (k3 > k2) k2 = k3;
            if (k2 > k0) k0 = k2;
            far = (int)(~(uint_t)k0) & (NPTS - 1);
        }
    }
}

// ---------------------------------------------------------------------------
// MFMA PAConv GEMM v11 (layers 1 and 2): v10 algebra, register-budgeted.
//   out[row,o] = sum_m S[row,m] * (sum_c F[row,c] * bank[m,c,o])
// - Stage relu(BN(F)) bf16 ONCE; As read-only after one barrier (0 K-loop
//   barriers). Rows padded to PADC=CIN+8 (odd 16B multiple): af[mi] is a
//   single aligned ds_read_b128, bank-rotated (2-way = free).
// - NTWE=2 col-tiles/wave (L2 column-split across 2x blocks): acc[4][2]=32,
//   a2[4][2]=32 (reset per m), Bf dbuf 16, af 16 transient, Sv 16 -> ~140
//   VGPR total. R8's spill (VGPR 128 + 1GB scratch WRITE) came from the
//   unbudgeted af[CCM][4]+acc[4][4] plan.
// - Bf parity = cc&1 (CCM even): all array indices compile-time (rule #20).
// ---------------------------------------------------------------------------
template<int LAYER, int CIN, int COUT, int CSPLIT>
__global__ __launch_bounds__(256) void gemm_kernel(const float* __restrict__ gamma,
                                                   const float* __restrict__ beta,
                                                   float* __restrict__ dout) {
    const float* __restrict__ A = (LAYER == 1) ? g_act1 : g_act2;
    float* __restrict__ O = (LAYER == 1) ? g_act2 : dout;
    constexpr int NTT = COUT / 16;            // global col tiles
    constexpr int NTWE = NTT / 4 / CSPLIT;    // col tiles per wave (= 2)
    constexpr int CCM = CIN / 32;             // K-chunks per m
    constexpr int NK = 8 * CCM;               // total K-chunk steps
    constexpr int PADC = CIN + 8;             // row stride: odd multiple of 16B
    constexpr int CPT = CIN / 4;              // staged elems per thread
    constexpr int BOFF = (LAYER == 1) ? B1_OFF : B2_OFF;
    __shared__ ushort_t As[64][PADC];
    __shared__ float s_scale[CIN];
    __shared__ float s_shift[CIN];
    __shared__ float s_rs[(LAYER < 2) ? COUT : 1];
    __shared__ float s_rss[(LAYER < 2) ? COUT : 1];

    const int t = threadIdx.x;
    const int lane = t & 63, w = t >> 6;
    const int q = lane >> 4, nlo = lane & 15;
    const int rowblk = (int)blockIdx.x / CSPLIT;
    const int csel = (int)blockIdx.x % CSPLIT;
    const int row0 = rowblk * 64;
    const int ntg0 = csel * (NTT / CSPLIT) + w * NTWE;   // wave's first global col tile
    const int arow_i = t >> 2, acg = t & 3;

    if constexpr (LAYER == 2) {
        // zero L0-stat region for the next rep (no reader in this rep's
        // remaining launches; next adders are next rep's mega knn blocks).
        if (blockIdx.x == 0 && t < 128) g_sums[t] = 0.0f;
    }

    {
        const float* sb = (LAYER == 1) ? g_sums : (g_sums + 256);
        if (t < CIN) {
            float mu  = sb[t] * (1.0f / 65536.0f);
            float var = sb[CIN + t] * (1.0f / 65536.0f) - mu * mu;
            var = fmaxf(var, 0.0f);
            float sc = gamma[t] / sqrtf(var + 1e-5f);
            s_scale[t] = sc;
            s_shift[t] = beta[t] - mu * sc;
        }
        __syncthreads();
    }

    // ---- stage relu(BN(F)) -> bf16, ONCE ----
    {
        const size_t arow = (size_t)(row0 + arow_i) * CIN;
        const float* ap = A + arow + acg * CPT;
        uint_t* dst = reinterpret_cast<uint_t*>(&As[arow_i][acg * CPT]);
        #pragma unroll
        for (int jj = 0; jj < CPT; jj += 8) {
            float4 fa = *reinterpret_cast<const float4*>(ap + jj);
            float4 fb = *reinterpret_cast<const float4*>(ap + jj + 4);
            float v[8] = {fa.x, fa.y, fa.z, fa.w, fb.x, fb.y, fb.z, fb.w};
            #pragma unroll
            for (int k2 = 0; k2 < 8; ++k2) {
                const int c = acg * CPT + jj + k2;
                v[k2] = fmaxf(v[k2] * s_scale[c] + s_shift[c], 0.f);
            }
            #pragma unroll
            for (int k2 = 0; k2 < 8; k2 += 2)
                dst[(jj + k2) >> 1] = (uint_t)f2bf(v[k2]) | ((uint_t)f2bf(v[k2+1]) << 16);
        }
    }
    LDS_BARRIER();

    union FragU { uint4 u4; short8 s; };
    f32x4 acc[4][NTWE];
    #pragma unroll
    for (int mi = 0; mi < 4; ++mi)
        #pragma unroll
        for (int ni = 0; ni < NTWE; ++ni) acc[mi][ni] = (f32x4){0.f, 0.f, 0.f, 0.f};

    const ushort_t* fbase = g_bankF + BOFF + lane * 8;
    const float* Sbase = g_S + (size_t)LAYER * 8 * NROWS;

    FragU Bf[2][NTWE];
    #pragma unroll
    for (int ni = 0; ni < NTWE; ++ni)
        Bf[0][ni].u4 = *reinterpret_cast<const uint4*>(
            fbase + (size_t)(ntg0 + ni) * 512);

    for (int m = 0; m < 8; ++m) {
        f32x4 Sv[4];
        #pragma unroll
        for (int mi = 0; mi < 4; ++mi)
            Sv[mi] = *reinterpret_cast<const f32x4*>(
                Sbase + (size_t)m * NROWS + row0 + mi*16 + q*4);
        f32x4 a2[4][NTWE];
        #pragma unroll
        for (int mi = 0; mi < 4; ++mi)
            #pragma unroll
            for (int ni = 0; ni < NTWE; ++ni) a2[mi][ni] = (f32x4){0.f, 0.f, 0.f, 0.f};
        #pragma unroll
        for (int cc = 0; cc < CCM; ++cc) {
            const int s = m * CCM + cc;   // == kc; parity s&1 == cc&1 (CCM even)
            if (s + 1 < NK) {
                #pragma unroll
                for (int ni = 0; ni < NTWE; ++ni)
                    Bf[(cc + 1) & 1][ni].u4 = *reinterpret_cast<const uint4*>(
                        fbase + (size_t)((s + 1) * NTT + ntg0 + ni) * 512);
            }
            FragU af[4];
            #pragma unroll
            for (int mi = 0; mi < 4; ++mi)
                af[mi].u4 = *reinterpret_cast<const uint4*>(&As[mi*16 + nlo][cc*32 + q*8]);
            #pragma unroll
            for (int ni = 0; ni < NTWE; ++ni)
                #pragma unroll
                for (int mi = 0; mi < 4; ++mi)
                    a2[mi][ni] = __builtin_amdgcn_mfma_f32_16x16x32_bf16(
                        af[mi].s, Bf[cc & 1][ni].s, a2[mi][ni], 0, 0, 0);
        }
        #pragma unroll
        for (int mi = 0; mi < 4; ++mi)
            #pragma unroll
            for (int ni = 0; ni < NTWE; ++ni)
                acc[mi][ni] += Sv[mi] * a2[mi][ni];   // f32 combine (per-row score)
    }

    if constexpr (LAYER == 2) {
        const int bp0 = row0 >> 4;
        #pragma unroll
        for (int mi = 0; mi < 4; ++mi) {
            const int bp = bp0 + mi;
            const int b = bp >> 9, p = bp & 511;
            #pragma unroll
            for (int ni = 0; ni < NTWE; ++ni) {
                float mv = fmaxf(fmaxf(acc[mi][ni][0], acc[mi][ni][1]),
                                 fmaxf(acc[mi][ni][2], acc[mi][ni][3]));
                mv = fmaxf(mv, __shfl_xor(mv, 16));
                mv = fmaxf(mv, __shfl_xor(mv, 32));
                if (lane < 16) {
                    const int col = (ntg0 + ni) * 16 + nlo;
                    O[(size_t)(b * 256 + col) * NPOINT + p] = mv;
                }
            }
        }
    } else {
        #pragma unroll
        for (int mi = 0; mi < 4; ++mi)
            #pragma unroll
            for (int ni = 0; ni < NTWE; ++ni)
                #pragma unroll
                for (int r2 = 0; r2 < 4; ++r2)
                    O[(size_t)(row0 + mi*16 + q*4 + r2) * COUT + (ntg0 + ni)*16 + nlo] = acc[mi][ni][r2];
        #pragma unroll
        for (int ni = 0; ni < NTWE; ++ni) {
            float s = 0.f, ss = 0.f;
            #pragma unroll
            for (int mi = 0; mi < 4; ++mi) {
                #pragma unroll
                for (int r2 = 0; r2 < 4; ++r2) {
                    float x = acc[mi][ni][r2];
                    s += x; ss += x * x;
                }
            }
            s  += __shfl_xor(s, 16);  s  += __shfl_xor(s, 32);
            ss += __shfl_xor(ss, 16); ss += __shfl_xor(ss, 32);
            if (q == 0) {
                const int c = (ntg0 + ni) * 16 + nlo;   // unique owner
                s_rs[c] = s;
                s_rss[c] = ss;
            }
        }
        __syncthreads();
        if (t < COUT) {
            float* sb = g_sums + 256;
            atomicAdd(&sb[t], s_rs[t]);
            atomicAdd(&sb[COUT + t], s_rss[t]);
        }
    }
}

// ---------------------------------------------------------------------------
extern "C" void kernel_launch(void* const* d_in, const int* in_sizes, int n_in,
                              void* d_out, int out_size, void* d_ws, size_t ws_size,
                              hipStream_t stream) {
    const float* xyz    = (const float*)d_in[0];
    const float* nrm    = (const float*)d_in[1];
    const float* Xa     = (const float*)d_in[2];
    const float* Ya     = (const float*)d_in[3];
    const float* points = (const float*)d_in[4];
    const float* w1_0 = (const float*)d_in[5];  const float* b1_0 = (const float*)d_in[6];
    const float* w2_0 = (const float*)d_in[7];  const float* b2_0 = (const float*)d_in[8];
    const float* bank0 = (const float*)d_in[9];
    const float* g0 = (const float*)d_in[10];   const float* be0 = (const float*)d_in[11];
    const float* w1_1 = (const float*)d_in[12]; const float* b1_1 = (const float*)d_in[13];
    const float* w2_1 = (const float*)d_in[14]; const float* b2_1 = (const float*)d_in[15];
    const float* bank1 = (const float*)d_in[16];
    const float* g1 = (const float*)d_in[17];   const float* be1 = (const float*)d_in[18];
    const float* w1_2 = (const float*)d_in[19]; const float* b1_2 = (const float*)d_in[20];
    const float* w2_2 = (const float*)d_in[21]; const float* b2_2 = (const float*)d_in[22];
    const float* bank2 = (const float*)d_in[23];
    float* out = (float*)d_out;
    (void)d_ws; (void)ws_size; (void)in_sizes; (void)n_in; (void)out_size;

    // mega: fps + transpose + zero(L1 stats) + bank conv + knn/score/small_out/L0-GEMM
    mega_kernel<<<MEGA_GRID, 256, 0, stream>>>(xyz, points, bank0, bank1, bank2, out,
                                               nrm, Xa, Ya,
                                               w1_0, b1_0, w2_0, b2_0,
                                               w1_1, b1_1, w2_1, b2_1,
                                               w1_2, b1_2, w2_2, b2_2);
    // layer 1 (v11): BN0+relu staged once -> raw act2 + BN stats
    gemm_kernel<1, 64, 128, 1><<<1024, 256, 0, stream>>>(g0, be0, nullptr);
    // layer 2 (v11): column-split 2x -> fused max-k + transpose to d_out
    //                (also zeroes L0-stat region for the next rep)
    gemm_kernel<2, 128, 256, 2><<<2048, 256, 0, stream>>>(g1, be1, out + 49152);
}

// Round 11
// 433.164 us; speedup vs baseline: 2.2505x; 1.1027x over previous
//
#include <hip/hip_runtime.h>
#include <math.h>

#define NBATCH 8
#define NPTS   2048
#define NPOINT 512
#define KNB    16
#define NROWS  (NBATCH*NPOINT*KNB)   // 65536

// mega-kernel block roles
#define TRANS_BASE  NBATCH          // 8..263   transpose (256)
#define ZERO_BID    (NBATCH + 256)  // 264      zero L1-stat region
#define CONV_BASE   (NBATCH + 257)  // 265..968 bank conv (704 blocks, pair-wise)
#define KNN_BASE    (NBATCH + 257 + 704)    // 969..1992 knn+score+L0 (1024 blocks)
#define MEGA_GRID   (KNN_BASE + 1024)       // 1993
#define RCTR_TARGET 960             // 256 transpose + 704 conv

typedef unsigned short ushort_t;
typedef unsigned int   uint_t;
typedef unsigned long long ull_t;
typedef __attribute__((ext_vector_type(8))) short  short8;   // 8 bf16 (4 VGPRs)
typedef __attribute__((ext_vector_type(4))) float  f32x4;    // MFMA C/D
typedef __attribute__((ext_vector_type(2))) float  f32x2;    // packed-FP32 pair

// g_bankF element offsets (bf16, MFMA-fragment-major: [kc][nt][lane][8])
#define B0_OFF 0        // COUT=64,  K=512  -> 32768 elems
#define B1_OFF 32768    // COUT=128, K=512  -> 65536
#define B2_OFF 98304    // COUT=256, K=1024 -> 262144
#define BT_TOT 360448

// LDS-only workgroup barrier: orders LDS ops across waves WITHOUT draining
// vmcnt, so global loads stay in flight.
#define LDS_BARRIER() asm volatile("s_waitcnt lgkmcnt(0)\n\ts_barrier" ::: "memory")

// ---------------------------------------------------------------------------
// Scratch in static __device__ globals. g_S layout: [l][m][row].
// ---------------------------------------------------------------------------
__device__ __align__(16) int      g_fidx [NBATCH * NPOINT];       //  16 KB
__device__ __align__(16) int      g_fready[NBATCH * NPOINT];      //  16 KB flags
__device__            int      g_rctr = 0;                        // arrival counter (monotonic across reps)
__device__ __align__(16) int      g_knn [NROWS];                  // 256 KB
__device__ __align__(16) float    g_sums[1024];                   //   4 KB  [0,128)=L0 stats, [256,512)=L1 stats
__device__ __align__(16) float    g_pT  [NBATCH * NPTS * 64];     //   4 MB
__device__ __align__(16) float    g_S   [(size_t)3 * 8 * NROWS];  //   6 MB  [l][m][row]
__device__ __align__(16) float    g_act1[(size_t)NROWS * 64];     //  16 MB
__device__ __align__(16) float    g_act2[(size_t)NROWS * 128];    //  32 MB
__device__ __align__(16) ushort_t g_bankF[BT_TOT];                // 704 KB bf16 fragments

// f32 -> bf16 round-to-nearest-even (finite inputs).
__device__ __forceinline__ ushort_t f2bf(float f) {
    uint_t u = __float_as_uint(f);
    return (ushort_t)((u + 0x7FFFu + ((u >> 16) & 1u)) >> 16);
}

// DPP-shifted copy of a u64 key (bound_ctrl=1: invalid lanes read 0).
template<int CTRL>
__device__ __forceinline__ ull_t dpp_u64(ull_t k) {
    int lo = (int)(uint_t)k;
    int hi = (int)(uint_t)(k >> 32);
    int slo = __builtin_amdgcn_update_dpp(0, lo, CTRL, 0xF, 0xF, true);
    int shi = __builtin_amdgcn_update_dpp(0, hi, CTRL, 0xF, 0xF, true);
    return ((ull_t)(uint_t)shi << 32) | (uint_t)slo;
}

__device__ __forceinline__ ull_t dpp_max_u64(ull_t key) {
    { ull_t s = dpp_u64<0x111>(key); if (s > key) key = s; }  // row_shr:1
    { ull_t s = dpp_u64<0x112>(key); if (s > key) key = s; }  // row_shr:2
    { ull_t s = dpp_u64<0x114>(key); if (s > key) key = s; }  // row_shr:4
    { ull_t s = dpp_u64<0x118>(key); if (s > key) key = s; }  // row_shr:8
    { ull_t s = dpp_u64<0x142>(key); if (s > key) key = s; }  // row_bcast:15
    { ull_t s = dpp_u64<0x143>(key); if (s > key) key = s; }  // row_bcast:31
    return key;   // wave max in lane 63
}

template<int CTRL>
__device__ __forceinline__ uint_t dpp_u32(uint_t v) {
    return (uint_t)__builtin_amdgcn_update_dpp(0, (int)v, CTRL, 0xF, 0xF, true);
}

__device__ __forceinline__ uint_t dpp_max_u32(uint_t v) {
    { uint_t s = dpp_u32<0x111>(v); if (s > v) v = s; }
    { uint_t s = dpp_u32<0x112>(v); if (s > v) v = s; }
    { uint_t s = dpp_u32<0x114>(v); if (s > v) v = s; }
    { uint_t s = dpp_u32<0x118>(v); if (s > v) v = s; }
    { uint_t s = dpp_u32<0x142>(v); if (s > v) v = s; }
    { uint_t s = dpp_u32<0x143>(v); if (s > v) v = s; }
    return v;   // wave max in lane 63
}

// Convert one bank element PAIR into fragment-major bf16 layout.
template<int COUT>
__device__ __forceinline__ void bank_frag2(const float* __restrict__ bank,
                                           uint_t* __restrict__ dst, int le) {
    const int j = le & 7;
    const int lane = (le >> 3) & 63;
    const int rem = le >> 9;
    constexpr int NTL = COUT / 16;
    const int nt = rem % NTL;
    const int kc = rem / NTL;
    const int q = lane >> 4, nlo = lane & 15;
    const int k = kc * 32 + q * 8 + j;
    const int n = nt * 16 + nlo;
    const float f0 = bank[(size_t)k * COUT + n];
    const float f1 = bank[(size_t)(k + 1) * COUT + n];
    dst[le >> 1] = (uint_t)f2bf(f0) | ((uint_t)f2bf(f1) << 16);
}

// ---------------------------------------------------------------------------
// mega_kernel: R9-verified form, unchanged.
// ---------------------------------------------------------------------------
__global__ __launch_bounds__(256, 5) void mega_kernel(
    const float* __restrict__ xyz, const float* __restrict__ points,
    const float* __restrict__ bank0, const float* __restrict__ bank1,
    const float* __restrict__ bank2, float* __restrict__ dout,
    const float* __restrict__ nrm, const float* __restrict__ Xa,
    const float* __restrict__ Ya,
    const float* __restrict__ w1_0, const float* __restrict__ b1_0,
    const float* __restrict__ w2_0, const float* __restrict__ b2_0,
    const float* __restrict__ w1_1, const float* __restrict__ b1_1,
    const float* __restrict__ w2_1, const float* __restrict__ b2_1,
    const float* __restrict__ w1_2, const float* __restrict__ b1_2,
    const float* __restrict__ w2_2, const float* __restrict__ b2_2) {
    __shared__ float smem[3 * NPTS];     // 24 KB, multi-role
    __shared__ ull_t s_key[2][4];
    const int bid = blockIdx.x;
    const int t = threadIdx.x;

    if (bid >= NBATCH) {
        if (bid < ZERO_BID) {
            // ---- transpose points (one 64x64 tile, 16 elems/thread) ----
            float (*tile)[65] = reinterpret_cast<float(*)[65]>(smem);
            const int blk = bid - TRANS_BASE;
            const int b = blk >> 5;
            const int n0 = (blk & 31) * 64;
            const int lane = t & 63, q = t >> 6;   // q in [0,4)
            #pragma unroll
            for (int i = 0; i < 16; ++i) {
                int c = q * 16 + i;
                tile[c][lane] = points[(b * 64 + c) * NPTS + n0 + lane];
            }
            __syncthreads();
            #pragma unroll
            for (int i = 0; i < 16; ++i) {
                int n = q * 16 + i;
                g_pT[(size_t)(b * NPTS + n0 + n) * 64 + lane] = tile[lane][n];
            }
            __syncthreads();
            if (t == 0)
                __hip_atomic_fetch_add(&g_rctr, 1, __ATOMIC_RELEASE,
                                       __HIP_MEMORY_SCOPE_AGENT);
            return;
        } else if (bid == ZERO_BID) {
            g_sums[256 + t] = 0.0f;
            return;
        } else if (bid < KNN_BASE) {
            // ---- bank -> fragment-major bf16, element PAIRS (704 blocks) ----
            const int le = ((bid - CONV_BASE) * 256 + t) << 1;   // even elem idx
            if (le < 32768) {
                bank_frag2<64>(bank0, reinterpret_cast<uint_t*>(g_bankF + B0_OFF), le);
            } else if (le < 98304) {
                bank_frag2<128>(bank1, reinterpret_cast<uint_t*>(g_bankF + B1_OFF), le - 32768);
            } else {
                bank_frag2<256>(bank2, reinterpret_cast<uint_t*>(g_bankF + B2_OFF), le - 98304);
            }
            __syncthreads();
            if (t == 0)
                __hip_atomic_fetch_add(&g_rctr, 1, __ATOMIC_RELEASE,
                                       __HIP_MEMORY_SCOPE_AGENT);
            return;
        }

        // ============ knn + score + small_out + fused L0 GEMM ============
        {
            const float* w1p[3] = {w1_0, w1_1, w1_2};
            const float* b1p[3] = {b1_0, b1_1, b1_2};
            const float* w2p[3] = {w2_0, w2_1, w2_2};
            const float* b2p[3] = {b2_0, b2_1, b2_2};
            #pragma unroll
            for (int l = 0; l < 3; ++l) {
                if (t < 160) smem[l * 160 + t] = w1p[l][t];
                if (t < 16)  smem[480 + l * 16 + t] = b1p[l][t];
                if (t < 128) smem[528 + l * 128 + t] = w2p[l][t];
                if (t < 8)   smem[912 + l * 8 + t] = b2p[l][t];
            }
        }
        __syncthreads();

        const int wave = (bid - KNN_BASE) * 4 + (t >> 6);   // = b*512 + p
        const int lane = t & 63;
        const int b = wave >> 9;
        const int p = wave & 511;
        const float* xb = xyz + b * 3 * NPTS;

        // ---- spin until FPS publishes this query ----
        int fv = __hip_atomic_load(&g_fready[wave], __ATOMIC_RELAXED,
                                   __HIP_MEMORY_SCOPE_AGENT);
        while (fv == 0) {
            __builtin_amdgcn_s_sleep(15);
            fv = __hip_atomic_load(&g_fready[wave], __ATOMIC_RELAXED,
                                   __HIP_MEMORY_SCOPE_AGENT);
        }
        if (lane == 0)
            __hip_atomic_store(&g_fready[wave], 0, __ATOMIC_RELAXED,
                               __HIP_MEMORY_SCOPE_AGENT);
        const int fi = (fv - 1) & (NPTS - 1);
        int nmine = 0;

        {
            #pragma clang fp contract(off)
            float ax = xb[fi];
            float ay = xb[NPTS + fi];
            float az = xb[2*NPTS + fi];
            float sa = ax*ax + ay*ay; sa = sa + az*az;
            float d[32];
            #pragma unroll
            for (int j = 0; j < 32; ++j) {
                int pp = j * 64 + lane;
                float bx = xb[pp];
                float by = xb[NPTS + pp];
                float bz = xb[2*NPTS + pp];
                float sb = bx*bx + by*by; sb = sb + bz*bz;
                float dot = ax*bx + ay*by; dot = dot + az*bz;
                float t1 = sa + sb;
                float t2 = 2.0f * dot;
                d[j] = t1 - t2;
            }
            for (int r = 0; r < KNB; ++r) {
                float best = 1e30f; int bi = 0x7fffffff;
                #pragma unroll
                for (int j = 0; j < 32; ++j) {
                    if (d[j] < best) { best = d[j]; bi = j * 64 + lane; }
                }
                uint_t ub = __float_as_uint(best);
                ub = (ub & 0x80000000u) ? ~ub : (ub | 0x80000000u);
                ull_t key = ((ull_t)(~ub) << 32) | (uint_t)(~bi);
                key = dpp_max_u64(key);
                uint_t wlo = (uint_t)__builtin_amdgcn_readlane((int)(uint_t)key, 63);
                bi = (int)(~wlo) & (NPTS - 1);
                if (lane == 0) g_knn[wave * KNB + r] = bi;
                if (lane == r) nmine = bi;
                int rl = bi & 63, rs = bi >> 6;
                if (lane == rl) {
                    #pragma unroll
                    for (int j = 0; j < 32; ++j) if (j == rs) d[j] = 1e30f;
                }
            }
        }

        // ---- small outputs for this query ----
        {
            const int n0 = __builtin_amdgcn_readlane(nmine, 0) & (NPTS - 1);
            if (lane < 12) {
                const int arr = lane / 3, a = lane % 3;
                const float* src = (arr == 0) ? xyz : (arr == 1) ? nrm
                                 : (arr == 2) ? Xa : Ya;
                const int idx = (arr == 0) ? fi : n0;
                dout[arr * 12288 + (b*3 + a) * NPOINT + p] =
                    src[(b*3 + a) * NPTS + idx];
            }
        }

        // ---- score phase: lanes 0-15 each handle row (b,p,k=lane) ----
        if (lane < 16) {
            const int row = wave * KNB + lane;
            const int n = nmine & (NPTS - 1);
            const float* nb = nrm + b * 3 * NPTS;
            const float* Xb = Xa  + b * 3 * NPTS;
            const float* Yb = Ya  + b * 3 * NPTS;
            float gx, gy, gz, sq, draw, nnv;
            {
                #pragma clang fp contract(off)
                gx = xb[n]        - xb[fi];
                gy = xb[NPTS + n] - xb[NPTS + fi];
                gz = xb[2*NPTS+n] - xb[2*NPTS+fi];
                sq = gx*gx + gy*gy;
                sq = sq + gz*gz;
                draw = sqrtf(sq + 1e-10f);
                nnv = sqrtf(sq);
            }
            float dmin = draw, dmax = draw;
            #pragma unroll
            for (int m = 1; m < 16; m <<= 1) {
                dmin = fminf(dmin, __shfl_xor(dmin, m, 16));
                dmax = fmaxf(dmax, __shfl_xor(dmax, m, 16));
            }
            float dist;
            {
                #pragma clang fp contract(off)
                dist = (draw - dmin) / ((dmax - dmin) + 1e-10f);
            }
            float nx = nb[n], ny = nb[NPTS+n], nz = nb[2*NPTS+n];
            float Xx = Xb[n], Xy = Xb[NPTS+n], Xz = Xb[2*NPTS+n];
            float Yx = Yb[n], Yy = Yb[NPTS+n], Yz = Yb[2*NPTS+n];
            float g[10];
            g[0]=gx; g[1]=gy; g[2]=gz; g[3]=dist; g[4]=nx; g[5]=ny; g[6]=nz;
            {
                float vs[3][3] = {{nx,ny,nz},{Xx,Xy,Xz},{Yx,Yy,Yz}};
                #pragma unroll
                for (int a = 0; a < 3; ++a) {
                    float vx=vs[a][0], vy=vs[a][1], vz=vs[a][2];
                    float dot, nv;
                    {
                        #pragma clang fp contract(off)
                        dot = gx*vx + gy*vy; dot = dot + gz*vz;
                        float s2 = vx*vx + vy*vy; s2 = s2 + vz*vz;
                        nv = sqrtf(s2);
                    }
                    float cc = dot / (nnv * nv + 1e-8f);
                    cc = fminf(1.0f, fmaxf(-1.0f, cc));
                    g[7+a] = acosf(cc) / 3.14159274101257324f;
                }
            }
            #pragma unroll
            for (int l = 0; l < 3; ++l) {
                float h[16];
                #pragma unroll
                for (int i = 0; i < 16; ++i) {
                    float a = smem[480 + l * 16 + i];
                    #pragma unroll
                    for (int j = 0; j < 10; ++j) a += smem[l * 160 + i * 10 + j] * g[j];
                    h[i] = fmaxf(a, 0.0f);
                }
                float e[8]; float mx = -1e30f;
                #pragma unroll
                for (int m = 0; m < 8; ++m) {
                    float a = smem[912 + l * 8 + m];
                    #pragma unroll
                    for (int j = 0; j < 16; ++j) a += smem[528 + l * 128 + m * 16 + j] * h[j];
                    e[m] = a; mx = fmaxf(mx, a);
                }
                float sum = 0.0f;
                #pragma unroll
                for (int m = 0; m < 8; ++m) { e[m] = expf(e[m] - mx); sum += e[m]; }
                // g_S layout [l][m][row]
                #pragma unroll
                for (int m = 0; m < 8; ++m)
                    g_S[((size_t)l * 8 + m) * NROWS + row] = e[m] / sum;
            }
        }

        // ---- all 4 waves rejoin; g_knn/g_S visible (same CU) ----
        __syncthreads();
        if (t == 0) {
            while (__hip_atomic_load(&g_rctr, __ATOMIC_ACQUIRE,
                                     __HIP_MEMORY_SCOPE_AGENT) < RCTR_TARGET)
                __builtin_amdgcn_s_sleep(8);
        }
        __syncthreads();

        // =================== fused L0 GEMM (CIN=64, COUT=64) ===================
        {
            constexpr int NTT0 = 4;   // COUT/16
            constexpr int CCM0 = 2;   // CIN/32
            ushort_t (*AsP)[64][36] = reinterpret_cast<ushort_t(*)[64][36]>(smem + 1024);
            float* s_rs  = smem + 3328;
            float* s_rss = smem + 3392;
            const int w = t >> 6;
            const int q = lane >> 4, nlo = lane & 15;
            const int row0 = (bid - KNN_BASE) * 64;
            const int arow_i = t >> 2, acg = t & 3;
            const int rr = row0 + arow_i;
            const int rb = rr >> 13;
            const int rn = g_knn[rr] & (NPTS - 1);
            const size_t arow = (size_t)(rb * NPTS + rn) * 64;
            float svv[8];
            #pragma unroll
            for (int m = 0; m < 8; ++m) svv[m] = g_S[(size_t)m * NROWS + rr];
            f32x4 acc[4];
            #pragma unroll
            for (int mi = 0; mi < 4; ++mi) acc[mi] = (f32x4){0.f, 0.f, 0.f, 0.f};
            const ushort_t* fbase = g_bankF + B0_OFF + lane * 8;
            union FragU { uint4 u4; uint2 u2[2]; short8 s; };
            FragU B[2];
            B[0].u4 = *reinterpret_cast<const uint4*>(fbase + (size_t)w * 512);
            float vraw[8], vnext[8];
            {
                const float* ap = g_pT + arow + acg * 8;
                float4 fa = *reinterpret_cast<const float4*>(ap);
                float4 fb = *reinterpret_cast<const float4*>(ap + 4);
                vraw[0]=fa.x; vraw[1]=fa.y; vraw[2]=fa.z; vraw[3]=fa.w;
                vraw[4]=fb.x; vraw[5]=fb.y; vraw[6]=fb.z; vraw[7]=fb.w;
            }
            int par = 0;
            for (int cc = 0; cc < CCM0; ++cc) {
                #pragma unroll
                for (int m = 0; m < 8; ++m) {
                    {
                        const float sv = svv[m];
                        uint_t* dst = reinterpret_cast<uint_t*>(&AsP[par][arow_i][acg * 8]);
                        #pragma unroll
                        for (int j = 0; j < 8; j += 2)
                            dst[j >> 1] = (uint_t)f2bf(sv * vraw[j]) |
                                          ((uint_t)f2bf(sv * vraw[j + 1]) << 16);
                    }
                    if (m == 0) {
                        const int ccn = (cc + 1 < CCM0) ? cc + 1 : cc;
                        const float* ap = g_pT + arow + ccn * 32 + acg * 8;
                        float4 fa = *reinterpret_cast<const float4*>(ap);
                        float4 fb = *reinterpret_cast<const float4*>(ap + 4);
                        vnext[0]=fa.x; vnext[1]=fa.y; vnext[2]=fa.z; vnext[3]=fa.w;
                        vnext[4]=fb.x; vnext[5]=fb.y; vnext[6]=fb.z; vnext[7]=fb.w;
                    }
                    {
                        const int kcn = (m < 7) ? ((m + 1) * CCM0 + cc)
                                                : ((cc + 1 < CCM0) ? (cc + 1) : 0);
                        B[(m + 1) & 1].u4 = *reinterpret_cast<const uint4*>(
                            fbase + (size_t)(kcn * NTT0 + w) * 512);
                    }
                    LDS_BARRIER();
                    FragU af[4];
                    #pragma unroll
                    for (int mi = 0; mi < 4; ++mi) {
                        af[mi].u2[0] = *reinterpret_cast<const uint2*>(&AsP[par][mi*16 + nlo][q*8]);
                        af[mi].u2[1] = *reinterpret_cast<const uint2*>(&AsP[par][mi*16 + nlo][q*8 + 4]);
                    }
                    #pragma unroll
                    for (int mi = 0; mi < 4; ++mi)
                        acc[mi] = __builtin_amdgcn_mfma_f32_16x16x32_bf16(
                            af[mi].s, B[m & 1].s, acc[mi], 0, 0, 0);
                    par ^= 1;
                }
                #pragma unroll
                for (int j = 0; j < 8; ++j) vraw[j] = vnext[j];
            }
            #pragma unroll
            for (int mi = 0; mi < 4; ++mi)
                #pragma unroll
                for (int r2 = 0; r2 < 4; ++r2)
                    g_act1[(size_t)(row0 + mi*16 + q*4 + r2) * 64 + w*16 + nlo] = acc[mi][r2];
            float s = 0.f, ss = 0.f;
            #pragma unroll
            for (int mi = 0; mi < 4; ++mi) {
                #pragma unroll
                for (int r2 = 0; r2 < 4; ++r2) {
                    float x = acc[mi][r2];
                    s += x; ss += x * x;
                }
            }
            s  += __shfl_xor(s, 16);  s  += __shfl_xor(s, 32);
            ss += __shfl_xor(ss, 16); ss += __shfl_xor(ss, 32);
            if (q == 0) {
                const int c = w * 16 + nlo;
                s_rs[c] = s;
                s_rss[c] = ss;
            }
            __syncthreads();
            if (t < 64) {
                atomicAdd(&g_sums[t], s_rs[t]);
                atomicAdd(&g_sums[64 + t], s_rss[t]);
            }
        }
        return;
    }

    // ==================== FPS: 4 waves, 8 pts/lane (p = t*8+j) ====================
    {
        #pragma clang fp contract(off)
        const int b = bid;
        const int lane = t & 63, w = t >> 6;   // 4 waves
        const float* xb = xyz + b * 3 * NPTS;
        float* s_x = smem;
        float* s_y = smem + NPTS;
        float* s_z = smem + 2 * NPTS;
        f32x2 xp[4], yp[4], zp[4];
        float d[8];
        {
            const float4* xq = reinterpret_cast<const float4*>(xb + t * 8);
            const float4* yq = reinterpret_cast<const float4*>(xb + NPTS + t * 8);
            const float4* zq = reinterpret_cast<const float4*>(xb + 2 * NPTS + t * 8);
            float4 a0 = xq[0], a1 = xq[1];
            float4 b0 = yq[0], b1 = yq[1];
            float4 c0 = zq[0], c1 = zq[1];
            xp[0] = (f32x2){a0.x, a0.y}; xp[1] = (f32x2){a0.z, a0.w};
            xp[2] = (f32x2){a1.x, a1.y}; xp[3] = (f32x2){a1.z, a1.w};
            yp[0] = (f32x2){b0.x, b0.y}; yp[1] = (f32x2){b0.z, b0.w};
            yp[2] = (f32x2){b1.x, b1.y}; yp[3] = (f32x2){b1.z, b1.w};
            zp[0] = (f32x2){c0.x, c0.y}; zp[1] = (f32x2){c0.z, c0.w};
            zp[2] = (f32x2){c1.x, c1.y}; zp[3] = (f32x2){c1.z, c1.w};
            *reinterpret_cast<float4*>(s_x + t * 8)     = a0;
            *reinterpret_cast<float4*>(s_x + t * 8 + 4) = a1;
            *reinterpret_cast<float4*>(s_y + t * 8)     = b0;
            *reinterpret_cast<float4*>(s_y + t * 8 + 4) = b1;
            *reinterpret_cast<float4*>(s_z + t * 8)     = c0;
            *reinterpret_cast<float4*>(s_z + t * 8 + 4) = c1;
            #pragma unroll
            for (int j = 0; j < 8; ++j) d[j] = 1e10f;
        }
        __syncthreads();
        __builtin_amdgcn_s_setprio(2);   // shield the serial chain
        int far = 0;
        for (int i = 0; i < NPOINT; ++i) {
            if (t == 0) {
                g_fidx[b * NPOINT + i] = far;
                __hip_atomic_store(&g_fready[b * NPOINT + i], far + 1,
                                   __ATOMIC_RELAXED, __HIP_MEMORY_SCOPE_AGENT);
            }
            const float cx = s_x[far], cy = s_y[far], cz = s_z[far];
            const f32x2 cxp = (f32x2){cx, cx};
            const f32x2 cyp = (f32x2){cy, cy};
            const f32x2 czp = (f32x2){cz, cz};
            uint_t bb = 0u;
            #pragma unroll
            for (int a = 0; a < 4; ++a) {
                f32x2 dx = xp[a] - cxp;           // v_pk ops, exact IEEE
                f32x2 dy = yp[a] - cyp;
                f32x2 dz = zp[a] - czp;
                f32x2 s2 = dx*dx + dy*dy;         // contract(off): no fma
                s2 = s2 + dz*dz;
                float dn0 = fminf(d[2*a],   s2[0]);
                float dn1 = fminf(d[2*a+1], s2[1]);
                d[2*a] = dn0; d[2*a+1] = dn1;
                uint_t u0 = __float_as_uint(dn0);  // d >= 0: bits monotone
                uint_t u1 = __float_as_uint(dn1);
                bb = (u0 > bb) ? u0 : bb;
                bb = (u1 > bb) ? u1 : bb;
            }
            uint_t wm = dpp_max_u32(bb);
            const uint_t wbits = (uint_t)__builtin_amdgcn_readlane((int)wm, 63);
            int li = 8;
            #pragma unroll
            for (int j = 7; j >= 0; --j)
                li = (__float_as_uint(d[j]) == wbits) ? j : li;
            ull_t mk = __ballot(li < 8);              // nonempty by construction
            const int fl = __ffsll((unsigned long long)mk) - 1;   // lowest lane
            const int wj = __builtin_amdgcn_readlane(li, fl);
            const int wp = (((w << 6) + fl) << 3) + wj;   // this wave's winner p
            if (lane == 0) s_key[i & 1][w] = ((ull_t)wbits << 32) | (uint_t)(~wp);
            LDS_BARRIER();
            const ull_t* kb = s_key[i & 1];
            ull_t k0 = kb[0], k1 = kb[1], k2 = kb[2], k3 = kb[3];
            if (k1 > k0) k0 = k1;
            if (k3 > k2) k2 = k3;
            if (k2 > k0) k0 = k2;
            far = (int)(~(uint_t)k0) & (NPTS - 1);
        }
    }
}

// ---------------------------------------------------------------------------
// MFMA PAConv GEMM v8-restored (layers 1 and 2): the R7-proven structure
// (168us chain). Only change vs R7: svv[] reads adapt to g_S [l][m][row].
// R8 (full-reg v10) spilled; R9 (budgeted v11) lost latency hiding -> both
// slower. v8's deep m-loop + small LDS + double-buffered staging is the
// best-measured structure for this problem shape.
// LAYER 2 additionally zeroes the L0-stat region [0,128) for the next rep.
// ---------------------------------------------------------------------------
template<int LAYER, int CIN, int COUT>
__global__ __launch_bounds__(256) void gemm_kernel(const float* __restrict__ gamma,
                                                   const float* __restrict__ beta,
                                                   float* __restrict__ dout) {
    const float* __restrict__ A = (LAYER == 1) ? g_act1 : g_act2;
    float* __restrict__ O = (LAYER == 1) ? g_act2 : dout;
    constexpr int NTT = COUT / 16;    // total col tiles
    constexpr int NTW = NTT / 4;      // col tiles per wave
    constexpr int CCM = CIN / 32;     // c-chunks
    constexpr int BOFF = (LAYER == 1) ? B1_OFF : B2_OFF;
    __shared__ ushort_t As[2][64][36];
    __shared__ float s_scale[CIN];
    __shared__ float s_shift[CIN];
    __shared__ float s_rs[(LAYER < 2) ? COUT : 1];
    __shared__ float s_rss[(LAYER < 2) ? COUT : 1];

    const int t = threadIdx.x;
    const int lane = t & 63, w = t >> 6;
    const int q = lane >> 4, nlo = lane & 15;
    const int row0 = blockIdx.x * 64;
    const int arow_i = t >> 2, acg = t & 3;

    if constexpr (LAYER == 2) {
        // zero L0-stat region for the next rep (no reader of [0,128) in this
        // or any later launch of this rep; next adders are next rep's mega).
        if (blockIdx.x == 0 && t < 128) g_sums[t] = 0.0f;
    }

    {
        const float* sb = (LAYER == 1) ? g_sums : (g_sums + 256);
        if (t < CIN) {
            float mu  = sb[t] * (1.0f / 65536.0f);
            float var = sb[CIN + t] * (1.0f / 65536.0f) - mu * mu;
            var = fmaxf(var, 0.0f);
            float sc = gamma[t] / sqrtf(var + 1e-5f);
            s_scale[t] = sc;
            s_shift[t] = beta[t] - mu * sc;
        }
        __syncthreads();
    }

    const size_t arow = (size_t)(row0 + arow_i) * CIN;
    const float* Sbase = g_S + (size_t)LAYER * 8 * NROWS;

    float svv[8];
    #pragma unroll
    for (int m = 0; m < 8; ++m)
        svv[m] = Sbase[(size_t)m * NROWS + row0 + arow_i];

    f32x4 acc[4][NTW];
    #pragma unroll
    for (int mi = 0; mi < 4; ++mi)
        #pragma unroll
        for (int ni = 0; ni < NTW; ++ni) acc[mi][ni] = (f32x4){0.f, 0.f, 0.f, 0.f};

    const ushort_t* fbase = g_bankF + BOFF + lane * 8;

    union FragU { uint4 u4; uint2 u2[2]; short8 s; };
    FragU B[2][NTW];
    // preload B for step 0 (kc=0)
    #pragma unroll
    for (int ni = 0; ni < NTW; ++ni)
        B[0][ni].u4 = *reinterpret_cast<const uint4*>(fbase + (size_t)(w * NTW + ni) * 512);

    // preload raw F chunk 0
    float vraw[8], vnext[8];
    {
        const float* ap = A + arow + acg * 8;
        float4 fa = *reinterpret_cast<const float4*>(ap);
        float4 fb = *reinterpret_cast<const float4*>(ap + 4);
        vraw[0]=fa.x; vraw[1]=fa.y; vraw[2]=fa.z; vraw[3]=fa.w;
        vraw[4]=fb.x; vraw[5]=fb.y; vraw[6]=fb.z; vraw[7]=fb.w;
    }

    int par = 0;
    for (int cc = 0; cc < CCM; ++cc) {
        // ---- BN+relu on the (prefetched) raw chunk ----
        float v[8];
        #pragma unroll
        for (int j = 0; j < 8; ++j) {
            const int c = cc * 32 + acg * 8 + j;
            v[j] = fmaxf(vraw[j] * s_scale[c] + s_shift[c], 0.f);
        }
        #pragma unroll
        for (int m = 0; m < 8; ++m) {
            // ---- stage A (sv[m]*F -> bf16) into parity buffer ----
            {
                const float sv = svv[m];
                uint_t* dst = reinterpret_cast<uint_t*>(&As[par][arow_i][acg * 8]);
                #pragma unroll
                for (int j = 0; j < 8; j += 2)
                    dst[j >> 1] = (uint_t)f2bf(sv * v[j]) | ((uint_t)f2bf(sv * v[j+1]) << 16);
            }
            // ---- prefetch next F chunk (7 steps of latency hiding) ----
            if (m == 0) {
                const int ccn = (cc + 1 < CCM) ? cc + 1 : cc;
                const float* ap = A + arow + ccn * 32 + acg * 8;
                float4 fa = *reinterpret_cast<const float4*>(ap);
                float4 fb = *reinterpret_cast<const float4*>(ap + 4);
                vnext[0]=fa.x; vnext[1]=fa.y; vnext[2]=fa.z; vnext[3]=fa.w;
                vnext[4]=fb.x; vnext[5]=fb.y; vnext[6]=fb.z; vnext[7]=fb.w;
            }
            // ---- prefetch next-step B fragments (before the barrier) ----
            {
                const int kcn = (m < 7) ? ((m + 1) * CCM + cc)
                                        : ((cc + 1 < CCM) ? (cc + 1) : 0);
                #pragma unroll
                for (int ni = 0; ni < NTW; ++ni)
                    B[(m + 1) & 1][ni].u4 = *reinterpret_cast<const uint4*>(
                        fbase + (size_t)(kcn * NTT + w * NTW + ni) * 512);
            }
            LDS_BARRIER();   // LDS-only: B loads stay in flight
            // ---- A fragments: all 4 row-tiles of the block ----
            FragU af[4];
            #pragma unroll
            for (int mi = 0; mi < 4; ++mi) {
                af[mi].u2[0] = *reinterpret_cast<const uint2*>(&As[par][mi*16 + nlo][q*8]);
                af[mi].u2[1] = *reinterpret_cast<const uint2*>(&As[par][mi*16 + nlo][q*8 + 4]);
            }
            #pragma unroll
            for (int ni = 0; ni < NTW; ++ni)
                #pragma unroll
                for (int mi = 0; mi < 4; ++mi)
                    acc[mi][ni] = __builtin_amdgcn_mfma_f32_16x16x32_bf16(
                        af[mi].s, B[m & 1][ni].s, acc[mi][ni], 0, 0, 0);
            par ^= 1;
        }
        #pragma unroll
        for (int j = 0; j < 8; ++j) vraw[j] = vnext[j];
    }

    if constexpr (LAYER == 2) {
        const int bp0 = row0 >> 4;
        #pragma unroll
        for (int mi = 0; mi < 4; ++mi) {
            const int bp = bp0 + mi;
            const int b = bp >> 9, p = bp & 511;
            #pragma unroll
            for (int ni = 0; ni < NTW; ++ni) {
                float mv = fmaxf(fmaxf(acc[mi][ni][0], acc[mi][ni][1]),
                                 fmaxf(acc[mi][ni][2], acc[mi][ni][3]));
                mv = fmaxf(mv, __shfl_xor(mv, 16));
                mv = fmaxf(mv, __shfl_xor(mv, 32));
                if (lane < 16) {
                    const int col = w * 64 + ni * 16 + nlo;
                    O[(size_t)(b * 256 + col) * NPOINT + p] = mv;
                }
            }
        }
    } else {
        #pragma unroll
        for (int mi = 0; mi < 4; ++mi)
            #pragma unroll
            for (int ni = 0; ni < NTW; ++ni)
                #pragma unroll
                for (int r2 = 0; r2 < 4; ++r2)
                    O[(size_t)(row0 + mi*16 + q*4 + r2) * COUT + w*NTW*16 + ni*16 + nlo] = acc[mi][ni][r2];
        #pragma unroll
        for (int ni = 0; ni < NTW; ++ni) {
            float s = 0.f, ss = 0.f;
            #pragma unroll
            for (int mi = 0; mi < 4; ++mi) {
                #pragma unroll
                for (int r2 = 0; r2 < 4; ++r2) {
                    float x = acc[mi][ni][r2];
                    s += x; ss += x * x;
                }
            }
            s  += __shfl_xor(s, 16);  s  += __shfl_xor(s, 32);
            ss += __shfl_xor(ss, 16); ss += __shfl_xor(ss, 32);
            if (q == 0) {
                const int c = w * NTW * 16 + ni * 16 + nlo;   // unique owner
                s_rs[c] = s;
                s_rss[c] = ss;
            }
        }
        __syncthreads();
        if (t < COUT) {
            float* sb = g_sums + 256;
            atomicAdd(&sb[t], s_rs[t]);
            atomicAdd(&sb[COUT + t], s_rss[t]);
        }
    }
}

// ---------------------------------------------------------------------------
extern "C" void kernel_launch(void* const* d_in, const int* in_sizes, int n_in,
                              void* d_out, int out_size, void* d_ws, size_t ws_size,
                              hipStream_t stream) {
    const float* xyz    = (const float*)d_in[0];
    const float* nrm    = (const float*)d_in[1];
    const float* Xa     = (const float*)d_in[2];
    const float* Ya     = (const float*)d_in[3];
    const float* points = (const float*)d_in[4];
    const float* w1_0 = (const float*)d_in[5];  const float* b1_0 = (const float*)d_in[6];
    const float* w2_0 = (const float*)d_in[7];  const float* b2_0 = (const float*)d_in[8];
    const float* bank0 = (const float*)d_in[9];
    const float* g0 = (const float*)d_in[10];   const float* be0 = (const float*)d_in[11];
    const float* w1_1 = (const float*)d_in[12]; const float* b1_1 = (const float*)d_in[13];
    const float* w2_1 = (const float*)d_in[14]; const float* b2_1 = (const float*)d_in[15];
    const float* bank1 = (const float*)d_in[16];
    const float* g1 = (const float*)d_in[17];   const float* be1 = (const float*)d_in[18];
    const float* w1_2 = (const float*)d_in[19]; const float* b1_2 = (const float*)d_in[20];
    const float* w2_2 = (const float*)d_in[21]; const float* b2_2 = (const float*)d_in[22];
    const float* bank2 = (const float*)d_in[23];
    float* out = (float*)d_out;
    (void)d_ws; (void)ws_size; (void)in_sizes; (void)n_in; (void)out_size;

    // mega: fps + transpose + zero(L1 stats) + bank conv + knn/score/small_out/L0-GEMM
    mega_kernel<<<MEGA_GRID, 256, 0, stream>>>(xyz, points, bank0, bank1, bank2, out,
                                               nrm, Xa, Ya,
                                               w1_0, b1_0, w2_0, b2_0,
                                               w1_1, b1_1, w2_1, b2_1,
                                               w1_2, b1_2, w2_2, b2_2);
    // layer 1 (v8): BN0+relu fused in staging -> raw act2 + BN stats
    gemm_kernel<1, 64, 128><<<1024, 256, 0, stream>>>(g0, be0, nullptr);
    // layer 2 (v8): BN1+relu fused in staging -> fused max-k + transpose to d_out
    //               (also zeroes L0-stat region for the next rep)
    gemm_kernel<2, 128, 256><<<1024, 256, 0, stream>>>(g1, be1, out + 49152);
}